// Round 1
// baseline (944.299 us; speedup 1.0000x reference)
//
#include <hip/hip_runtime.h>
#include <stdint.h>
#include <math.h>

typedef __attribute__((ext_vector_type(8))) short s16x8;
typedef __attribute__((ext_vector_type(4))) short s16x4;
typedef __attribute__((ext_vector_type(4))) float f32x4;

#define NEGH (-1.0e30f)

__device__ __forceinline__ short f2bf(float f) {
  union { float f; unsigned int i; } c; c.f = f;
  unsigned int lsb = (c.i >> 16) & 1u;
  c.i += 0x7fffu + lsb;
  return (short)(c.i >> 16);
}
__device__ __forceinline__ float bf2f(short u) {
  union { unsigned int i; float f; } c;
  c.i = ((unsigned int)(unsigned short)u) << 16;
  return c.f;
}

// async global->LDS, 16B per lane. LDS dest must be wave-uniform base + lane*16.
#define GLOAD_LDS16(gp, lp)                                                  \
  __builtin_amdgcn_global_load_lds(                                          \
      (__attribute__((address_space(1))) void*)(void*)(gp),                  \
      (__attribute__((address_space(3))) void*)(lp), 16, 0, 0)

// ---------------------------------------------------------------------------
// fp32 -> bf16 conversion, 4 elements/thread. n must be divisible by 1024.
// ---------------------------------------------------------------------------
__global__ __launch_bounds__(256) void cvt_kernel(const float* __restrict__ in,
                                                  short* __restrict__ out)
{
  const size_t i = ((size_t)blockIdx.x * 256 + threadIdx.x) * 4;
  const float4 v = *(const float4*)(in + i);
  s16x4 o = { f2bf(v.x), f2bf(v.y), f2bf(v.z), f2bf(v.w) };
  *(s16x4*)(out + i) = o;
}

// ---------------------------------------------------------------------------
// GEMM: C[M,N] = A[M,K] * W[N,K]^T + bias[N]   (A,W bf16; bias fp32; fp32 acc)
// 128x128 tile, BK=64, 256 threads (4 waves in 2x2), mfma 16x16x32 bf16.
// omode: 0 = bf16 C row-major; 1 = fp32 C row-major;
//        2 = bf16 scatter C^T as vt[(b*N + n)*2048 + s] with m = b*2048+s.
// ---------------------------------------------------------------------------
__global__ __launch_bounds__(256) void gemm_bt(
    const short* __restrict__ A, const short* __restrict__ W,
    const float* __restrict__ bias, void* __restrict__ C,
    int M, int N, int K, int omode)
{
  __shared__ __align__(16) short As[128 * 64];
  __shared__ __align__(16) short Bs[128 * 64];

  const int t = threadIdx.x;
  const int l = t & 63;
  const int w = t >> 6;
  const int lane16 = l & 15;
  const int quad = l >> 4;
  const int wm = w >> 1, wn = w & 1;
  const int mb0 = blockIdx.y * 128;
  const int nb0 = blockIdx.x * 128;

  const f32x4 zero = {0.f, 0.f, 0.f, 0.f};
  f32x4 acc[4][4];
#pragma unroll
  for (int i = 0; i < 4; ++i)
#pragma unroll
    for (int j = 0; j < 4; ++j) acc[i][j] = zero;

  // staging geometry: per issue 256 threads cover 32 rows x 8 segs(16B)
  const int sr = t >> 3;                 // row within 32-row issue block
  const int sp = t & 7;                  // 16B segment within row
  const short* Ag = A + (size_t)(mb0 + sr) * K + sp * 8;
  const short* Wg = W + (size_t)(nb0 + sr) * K + sp * 8;
  short* Al = As + t * 8;
  short* Bl = Bs + t * 8;

  const int nkt = K >> 6;
  for (int kt = 0; kt < nkt; ++kt) {
    __syncthreads();
    const int kof = kt * 64;
#pragma unroll
    for (int it = 0; it < 4; ++it) {
      GLOAD_LDS16(Ag + kof + (size_t)(it * 32) * K, Al + it * 2048);
      GLOAD_LDS16(Wg + kof + (size_t)(it * 32) * K, Bl + it * 2048);
    }
    __syncthreads();
#pragma unroll
    for (int kk = 0; kk < 2; ++kk) {
      s16x8 af[4], bf[4];
#pragma unroll
      for (int mi = 0; mi < 4; ++mi)
        af[mi] = *(const s16x8*)&As[(wm * 64 + mi * 16 + lane16) * 64 +
                                    kk * 32 + quad * 8];
#pragma unroll
      for (int ni = 0; ni < 4; ++ni)
        bf[ni] = *(const s16x8*)&Bs[(wn * 64 + ni * 16 + lane16) * 64 +
                                    kk * 32 + quad * 8];
#pragma unroll
      for (int mi = 0; mi < 4; ++mi)
#pragma unroll
        for (int ni = 0; ni < 4; ++ni)
          acc[mi][ni] = __builtin_amdgcn_mfma_f32_16x16x32_bf16(
              af[mi], bf[ni], acc[mi][ni], 0, 0, 0);
    }
  }

  // epilogue: C/D layout col=lane&15 (n), row=quad*4+reg (m)
#pragma unroll
  for (int ni = 0; ni < 4; ++ni) {
    const int n = nb0 + wn * 64 + ni * 16 + lane16;
    const float bv = bias[n];
#pragma unroll
    for (int mi = 0; mi < 4; ++mi) {
      const int m0 = mb0 + wm * 64 + mi * 16 + quad * 4;
#pragma unroll
      for (int r = 0; r < 4; ++r) {
        const int m = m0 + r;
        const float v = acc[mi][ni][r] + bv;
        if (omode == 0) {
          ((short*)C)[(size_t)m * N + n] = f2bf(v);
        } else if (omode == 1) {
          ((float*)C)[(size_t)m * N + n] = v;
        } else {
          // m = b*2048 + s ; vt[(b*N + n)*2048 + s]
          ((short*)C)[((size_t)(m >> 11) * N + n) * 2048 + (m & 2047)] = f2bf(v);
        }
      }
    }
  }
}

// ---------------------------------------------------------------------------
// RoPE in place on bf16 buf[row][head*128 + d], pairs (d, d+64), pos = row%2048.
// Accurate sincosf (arg reaches 2047 rad; native v_sin domain ends ~±804).
// ---------------------------------------------------------------------------
__global__ __launch_bounds__(256) void rope_kernel(short* __restrict__ buf,
                                                   int lognh)
{
  const int idx = blockIdx.x * 256 + threadIdx.x;
  const int d = idx & 63;
  const int rest = idx >> 6;            // row*nh + h
  const int row = rest >> lognh;
  const int pos = row & 2047;
  // inv_freq = 10000^(-d/64) = exp2(-d * log2(10000)/64)
  const float fr = (float)pos * exp2f((float)d * -0.20762050593048584f);
  float sn, cs;
  sincosf(fr, &sn, &cs);
  const size_t base = (size_t)rest * 128 + d;
  const float lo = bf2f(buf[base]);
  const float hi = bf2f(buf[base + 64]);
  buf[base]      = f2bf(lo * cs - hi * sn);
  buf[base + 64] = f2bf(hi * cs + lo * sn);
}

// ---------------------------------------------------------------------------
// Flash attention, causal, GQA (kv = h>>2). BARRIER-FREE version.
// Block: 128 q-rows for one (b,h); 4 waves, each a 32-row q strip (2x16 sub-
// strips). K/V fragments are loaded DIRECTLY from global (per-(b,kv) panels
// are 512 KB -> L2-resident; a 64-key tile is 16 KB -> L1-resident), so there
// is no K/V LDS staging and no __syncthreads at all. Each K/V fragment feeds
// 2 MFMAs (both substrips) -> 32 FLOP/B from cache. Only LDS use is the
// wave-private P->A-frag transpose round-trip (Psm). Waves have divergent
// trip counts: fully-masked tiles are skipped per-wave.
// In-place og==qg safe: each block reads only its own Q rows (into regs,
// before its only stores); blocks touch disjoint (row, head-col) cells.
// ---------------------------------------------------------------------------
__global__ __launch_bounds__(256, 2) void attn_kernel(
    const short* __restrict__ qg, const short* __restrict__ kg,
    const short* __restrict__ vtg, short* __restrict__ og)
{
  __shared__ __align__(16) short Psm[128 * 72];   // [q(128)][key(64)], pad 72

  const int t = threadIdx.x;
  const int l = t & 63;
  const int w = t >> 6;
  const int lane16 = l & 15;
  const int quad = l >> 4;
  const int qt = blockIdx.x, h = blockIdx.y, b = blockIdx.z;
  const int kv = h >> 2;
  const int qb0 = qt * 128;
  const int qw0 = qb0 + w * 32;

  // Q B-fragments (Q^T operand): lane holds Q[q=lane16][d=kk*32+quad*8+j]
  s16x8 qf[2][4];
#pragma unroll
  for (int s = 0; s < 2; ++s) {
    const short* qrow = qg +
        ((size_t)(b * 2048 + qw0 + s * 16 + lane16)) * 2048 + h * 128 + quad * 8;
#pragma unroll
    for (int kk = 0; kk < 4; ++kk) qf[s][kk] = *(const s16x8*)(qrow + kk * 32);
  }

  const f32x4 zero = {0.f, 0.f, 0.f, 0.f};
  f32x4 o[2][8];
#pragma unroll
  for (int s = 0; s < 2; ++s)
#pragma unroll
    for (int i = 0; i < 8; ++i) o[s][i] = zero;
  float m_i[2] = {NEGH, NEGH};
  float l_i[2] = {0.f, 0.f};

  const float SC = 0.08838834764831845f * 1.4426950408889634f; // rsqrt(128)*log2e

  // global fragment bases
  const short* kp = kg + ((size_t)(b * 2048)) * 512 + kv * 128 + quad * 8;
  const short* vp = vtg + ((size_t)(b * 512 + kv * 128 + lane16)) * 2048 + quad * 8;

  const int ntw = ((qw0 + 31) >> 6) + 1;   // tiles this wave (causal skip)
  for (int itl = 0; itl < ntw; ++itl) {
    const int kbase = itl * 64;

    // St = K_tile(64x128) * Q^T(128x16): C col=q=lane16, row=key=quad*4+r
    f32x4 st[2][4];
#pragma unroll
    for (int s = 0; s < 2; ++s)
#pragma unroll
      for (int mt = 0; mt < 4; ++mt) st[s][mt] = zero;
#pragma unroll
    for (int mt = 0; mt < 4; ++mt) {
#pragma unroll
      for (int kk = 0; kk < 4; ++kk) {
        const s16x8 a = *(const s16x8*)(kp +
            (size_t)(kbase + mt * 16 + lane16) * 512 + kk * 32);
        st[0][mt] = __builtin_amdgcn_mfma_f32_16x16x32_bf16(a, qf[0][kk],
                                                            st[0][mt], 0, 0, 0);
        st[1][mt] = __builtin_amdgcn_mfma_f32_16x16x32_bf16(a, qf[1][kk],
                                                            st[1][mt], 0, 0, 0);
      }
    }

    // online softmax (folded scale*log2e); masks finite -1e30
    const bool maskt = (kbase + 63 > qw0);   // wave-uniform: only final tile(s)
    float alpha[2];
#pragma unroll
    for (int s = 0; s < 2; ++s) {
      const int qabs = qw0 + s * 16 + lane16;
      float tl = NEGH;
#pragma unroll
      for (int mt = 0; mt < 4; ++mt)
#pragma unroll
        for (int r = 0; r < 4; ++r) {
          float xx = st[s][mt][r] * SC;
          if (maskt && (kbase + mt * 16 + quad * 4 + r) > qabs) xx = NEGH;
          st[s][mt][r] = xx;
          tl = fmaxf(tl, xx);
        }
      tl = fmaxf(tl, __shfl_xor(tl, 16));
      tl = fmaxf(tl, __shfl_xor(tl, 32));
      const float mnew = fmaxf(m_i[s], tl);
      alpha[s] = exp2f(m_i[s] - mnew);
      float rs = 0.f;
#pragma unroll
      for (int mt = 0; mt < 4; ++mt) {
        const float p0 = exp2f(st[s][mt][0] - mnew);
        const float p1 = exp2f(st[s][mt][1] - mnew);
        const float p2 = exp2f(st[s][mt][2] - mnew);
        const float p3 = exp2f(st[s][mt][3] - mnew);
        rs += (p0 + p1) + (p2 + p3);
        s16x4 pk = { f2bf(p0), f2bf(p1), f2bf(p2), f2bf(p3) };
        *(s16x4*)&Psm[(w * 32 + s * 16 + lane16) * 72 + mt * 16 + quad * 4] = pk;
      }
      rs += __shfl_xor(rs, 16);
      rs += __shfl_xor(rs, 32);
      l_i[s] = l_i[s] * alpha[s] + rs;
      m_i[s] = mnew;
    }

    // rescale O (O rows are q = quad*4+r; alpha lives at lane16=q)
#pragma unroll
    for (int s = 0; s < 2; ++s)
#pragma unroll
      for (int r = 0; r < 4; ++r) {
        const float ar = __shfl(alpha[s], quad * 4 + r);
#pragma unroll
        for (int nt = 0; nt < 8; ++nt) o[s][nt][r] *= ar;
      }

    // PV: O[q][d] += P[q][key] * Vt[d][key]  (V frags direct from global/L2)
#pragma unroll
    for (int kk = 0; kk < 2; ++kk) {
      const s16x8 pf0 =
          *(const s16x8*)&Psm[(w * 32 + lane16) * 72 + kk * 32 + quad * 8];
      const s16x8 pf1 =
          *(const s16x8*)&Psm[(w * 32 + 16 + lane16) * 72 + kk * 32 + quad * 8];
#pragma unroll
      for (int nt = 0; nt < 8; ++nt) {
        const s16x8 vf = *(const s16x8*)(vp +
            (size_t)(nt * 16) * 2048 + kbase + kk * 32);
        o[0][nt] = __builtin_amdgcn_mfma_f32_16x16x32_bf16(pf0, vf,
                                                           o[0][nt], 0, 0, 0);
        o[1][nt] = __builtin_amdgcn_mfma_f32_16x16x32_bf16(pf1, vf,
                                                           o[1][nt], 0, 0, 0);
      }
    }
  }

  // normalize and store: O row q = quad*4+r, col d = nt*16+lane16
#pragma unroll
  for (int s = 0; s < 2; ++s)
#pragma unroll
    for (int r = 0; r < 4; ++r) {
      const float lr = __shfl(l_i[s], quad * 4 + r);
      const float inv = 1.f / lr;
      const size_t base =
          ((size_t)(b * 2048 + qw0 + s * 16 + quad * 4 + r)) * 2048 +
          h * 128 + lane16;
#pragma unroll
      for (int nt = 0; nt < 8; ++nt) og[base + nt * 16] = f2bf(o[s][nt][r] * inv);
    }
}

// ---------------------------------------------------------------------------
extern "C" void kernel_launch(void* const* d_in, const int* in_sizes, int n_in,
                              void* d_out, int out_size, void* d_ws,
                              size_t ws_size, hipStream_t stream)
{
  const float* x  = (const float*)d_in[0];
  const float* wq = (const float*)d_in[1];
  const float* bq = (const float*)d_in[2];
  const float* wk = (const float*)d_in[3];
  const float* bk = (const float*)d_in[4];
  const float* wv = (const float*)d_in[5];
  const float* bv = (const float*)d_in[6];
  const float* wo = (const float*)d_in[7];
  const float* bo = (const float*)d_in[8];
  float* out = (float*)d_out;

  // ws layout (76 MiB used):
  //   xb  @0      32 MiB  [8192][2048] bf16; dead after V-proj -> wob reuses @0
  //   wqb @32MiB   8 MiB  [2048][2048] bf16
  //   wkb @40MiB   2 MiB  [512][2048]  bf16
  //   wvb @42MiB   2 MiB  [512][2048]  bf16
  //   qws @44MiB  32 MiB  [8192][2048] bf16; attention output in place
  // d_out (64 MiB fp32) doubles as scratch for K / Vt (dead before final GEMM):
  //   kws @out+0   8 MiB  [8192][512]  bf16
  //   vtw @out+8M  8 MiB  [b][kv*128][2048] bf16
  char* ws = (char*)d_ws;
  short* xb  = (short*)ws;
  short* wqb = (short*)(ws + (32ull << 20));
  short* wkb = (short*)(ws + (40ull << 20));
  short* wvb = (short*)(ws + (42ull << 20));
  short* qws = (short*)(ws + (44ull << 20));
  short* wob = xb;
  short* kws = (short*)d_out;
  short* vtw = (short*)((char*)d_out + (8ull << 20));

  const dim3 blk(256);
  // fp32 -> bf16 input conversions
  cvt_kernel<<<16384, blk, 0, stream>>>(x,  xb);   // 16.7M elems
  cvt_kernel<<<4096,  blk, 0, stream>>>(wq, wqb);  // 4.19M
  cvt_kernel<<<1024,  blk, 0, stream>>>(wk, wkb);  // 1.05M
  cvt_kernel<<<1024,  blk, 0, stream>>>(wv, wvb);  // 1.05M
  // projections (bf16 MFMA, fp32 bias)
  gemm_bt<<<dim3(16, 64), blk, 0, stream>>>(xb, wqb, bq, qws, 8192, 2048, 2048, 0);
  gemm_bt<<<dim3(4, 64),  blk, 0, stream>>>(xb, wkb, bk, kws, 8192, 512, 2048, 0);
  gemm_bt<<<dim3(4, 64),  blk, 0, stream>>>(xb, wvb, bv, vtw, 8192, 512, 2048, 2);
  // rope (q: nh=16 -> lognh 4; k: nh=4 -> lognh 2); v untouched
  rope_kernel<<<32768, blk, 0, stream>>>(qws, 4);
  rope_kernel<<<8192,  blk, 0, stream>>>(kws, 2);
  // wo conversion into xb's slot (xb dead after V-proj; stream-ordered)
  cvt_kernel<<<4096, blk, 0, stream>>>(wo, wob);   // 4.19M
  // attention (in place on qws; 128 q-rows/block, barrier-free)
  attn_kernel<<<dim3(16, 16, 4), blk, 0, stream>>>(qws, kws, vtw, qws);
  // output projection: fp32 C into d_out (kws/vtw dead now)
  gemm_bt<<<dim3(16, 64), blk, 0, stream>>>(qws, wob, bo, out, 8192, 2048, 2048, 1);
}

// Round 2
// 624.391 us; speedup vs baseline: 1.5124x; 1.5124x over previous
//
#include <hip/hip_runtime.h>
#include <stdint.h>
#include <math.h>

typedef __attribute__((ext_vector_type(8))) short s16x8;
typedef __attribute__((ext_vector_type(4))) short s16x4;
typedef __attribute__((ext_vector_type(4))) float f32x4;

#define NEGH (-1.0e30f)

__device__ __forceinline__ short f2bf(float f) {
  union { float f; unsigned int i; } c; c.f = f;
  unsigned int lsb = (c.i >> 16) & 1u;
  c.i += 0x7fffu + lsb;
  return (short)(c.i >> 16);
}
__device__ __forceinline__ float bf2f(short u) {
  union { unsigned int i; float f; } c;
  c.i = ((unsigned int)(unsigned short)u) << 16;
  return c.f;
}

// async global->LDS, 16B per lane. LDS dest must be wave-uniform base + lane*16.
#define GLOAD_LDS16(gp, lp)                                                  \
  __builtin_amdgcn_global_load_lds(                                          \
      (__attribute__((address_space(1))) void*)(void*)(gp),                  \
      (__attribute__((address_space(3))) void*)(lp), 16, 0, 0)

// ---------------------------------------------------------------------------
// fp32 -> bf16 conversion, 4 elements/thread. n must be divisible by 1024.
// ---------------------------------------------------------------------------
__global__ __launch_bounds__(256) void cvt_kernel(const float* __restrict__ in,
                                                  short* __restrict__ out)
{
  const size_t i = ((size_t)blockIdx.x * 256 + threadIdx.x) * 4;
  const float4 v = *(const float4*)(in + i);
  s16x4 o = { f2bf(v.x), f2bf(v.y), f2bf(v.z), f2bf(v.w) };
  *(s16x4*)(out + i) = o;
}

// ---------------------------------------------------------------------------
// GEMM: C[M,N] = A[M,K] * W[N,K]^T + bias[N]   (A,W bf16; bias fp32; fp32 acc)
// 128x128 tile, BK=64, 256 threads (4 waves in 2x2), mfma 16x16x32 bf16.
// omode: 0 = bf16 C row-major; 1 = fp32 C row-major;
//        2 = bf16 scatter C^T as vt[(b*N + n)*2048 + s] with m = b*2048+s.
// ---------------------------------------------------------------------------
__global__ __launch_bounds__(256) void gemm_bt(
    const short* __restrict__ A, const short* __restrict__ W,
    const float* __restrict__ bias, void* __restrict__ C,
    int M, int N, int K, int omode)
{
  __shared__ __align__(16) short As[128 * 64];
  __shared__ __align__(16) short Bs[128 * 64];

  const int t = threadIdx.x;
  const int l = t & 63;
  const int w = t >> 6;
  const int lane16 = l & 15;
  const int quad = l >> 4;
  const int wm = w >> 1, wn = w & 1;
  const int mb0 = blockIdx.y * 128;
  const int nb0 = blockIdx.x * 128;

  const f32x4 zero = {0.f, 0.f, 0.f, 0.f};
  f32x4 acc[4][4];
#pragma unroll
  for (int i = 0; i < 4; ++i)
#pragma unroll
    for (int j = 0; j < 4; ++j) acc[i][j] = zero;

  // staging geometry: per issue 256 threads cover 32 rows x 8 segs(16B)
  const int sr = t >> 3;                 // row within 32-row issue block
  const int sp = t & 7;                  // 16B segment within row
  const short* Ag = A + (size_t)(mb0 + sr) * K + sp * 8;
  const short* Wg = W + (size_t)(nb0 + sr) * K + sp * 8;
  short* Al = As + t * 8;
  short* Bl = Bs + t * 8;

  const int nkt = K >> 6;
  for (int kt = 0; kt < nkt; ++kt) {
    __syncthreads();
    const int kof = kt * 64;
#pragma unroll
    for (int it = 0; it < 4; ++it) {
      GLOAD_LDS16(Ag + kof + (size_t)(it * 32) * K, Al + it * 2048);
      GLOAD_LDS16(Wg + kof + (size_t)(it * 32) * K, Bl + it * 2048);
    }
    __syncthreads();
#pragma unroll
    for (int kk = 0; kk < 2; ++kk) {
      s16x8 af[4], bf[4];
#pragma unroll
      for (int mi = 0; mi < 4; ++mi)
        af[mi] = *(const s16x8*)&As[(wm * 64 + mi * 16 + lane16) * 64 +
                                    kk * 32 + quad * 8];
#pragma unroll
      for (int ni = 0; ni < 4; ++ni)
        bf[ni] = *(const s16x8*)&Bs[(wn * 64 + ni * 16 + lane16) * 64 +
                                    kk * 32 + quad * 8];
#pragma unroll
      for (int mi = 0; mi < 4; ++mi)
#pragma unroll
        for (int ni = 0; ni < 4; ++ni)
          acc[mi][ni] = __builtin_amdgcn_mfma_f32_16x16x32_bf16(
              af[mi], bf[ni], acc[mi][ni], 0, 0, 0);
    }
  }

  // epilogue: C/D layout col=lane&15 (n), row=quad*4+reg (m)
#pragma unroll
  for (int ni = 0; ni < 4; ++ni) {
    const int n = nb0 + wn * 64 + ni * 16 + lane16;
    const float bv = bias[n];
#pragma unroll
    for (int mi = 0; mi < 4; ++mi) {
      const int m0 = mb0 + wm * 64 + mi * 16 + quad * 4;
#pragma unroll
      for (int r = 0; r < 4; ++r) {
        const int m = m0 + r;
        const float v = acc[mi][ni][r] + bv;
        if (omode == 0) {
          ((short*)C)[(size_t)m * N + n] = f2bf(v);
        } else if (omode == 1) {
          ((float*)C)[(size_t)m * N + n] = v;
        } else {
          // m = b*2048 + s ; vt[(b*N + n)*2048 + s]
          ((short*)C)[((size_t)(m >> 11) * N + n) * 2048 + (m & 2047)] = f2bf(v);
        }
      }
    }
  }
}

// ---------------------------------------------------------------------------
// RoPE in place on bf16 buf[row][head*128 + d], pairs (d, d+64), pos = row%2048.
// Accurate sincosf (arg reaches 2047 rad; native v_sin domain ends ~±804).
// ---------------------------------------------------------------------------
__global__ __launch_bounds__(256) void rope_kernel(short* __restrict__ buf,
                                                   int lognh)
{
  const int idx = blockIdx.x * 256 + threadIdx.x;
  const int d = idx & 63;
  const int rest = idx >> 6;            // row*nh + h
  const int row = rest >> lognh;
  const int pos = row & 2047;
  // inv_freq = 10000^(-d/64) = exp2(-d * log2(10000)/64)
  const float fr = (float)pos * exp2f((float)d * -0.20762050593048584f);
  float sn, cs;
  sincosf(fr, &sn, &cs);
  const size_t base = (size_t)rest * 128 + d;
  const float lo = bf2f(buf[base]);
  const float hi = bf2f(buf[base + 64]);
  buf[base]      = f2bf(lo * cs - hi * sn);
  buf[base + 64] = f2bf(hi * cs + lo * sn);
}

// ---------------------------------------------------------------------------
// Flash attention, causal, GQA (kv = h>>2). LDS-staged + latency-overlapped.
// Block: 512 threads = 8 waves; processes TWO 128-row q strips (j and 15-j)
// for one (b,h) -> every block does exactly 34 k-tiles (perfect balance).
// Each wave owns a 16-row q strip. Per 64-key tile:
//   barrier -> issue next tile's K/V global loads into regs (overlap) ->
//   QK^T MFMA from swizzled Ksm -> in-reg online softmax -> P to wave-private
//   swizzled Psm -> PV MFMA from swizzled Vsm -> barrier -> ds_write next tile.
// Single-buffered K/V is race-free: writes land after the 2nd barrier, i.e.
// after every wave finished reading the current tile.
// XOR swizzle (col16B ^= row&7) keeps unpadded 256B/128B rows ~conflict-free.
// In-place og==qg safe: block reads only its own Q rows (into regs, at strip
// start) and stores only those same (row, head-col) cells at strip end.
// ---------------------------------------------------------------------------
__global__ __launch_bounds__(512, 4) void attn_kernel(
    const short* __restrict__ qg, const short* __restrict__ kg,
    const short* __restrict__ vtg, short* __restrict__ og)
{
  __shared__ __align__(16) short Ksm[64 * 128];   // [key][d], swizzled
  __shared__ __align__(16) short Vsm[128 * 64];   // [d][key], swizzled
  __shared__ __align__(16) short Psm[128 * 64];   // [q][key], swizzled, wave-private rows

  const int t = threadIdx.x;
  const int l = t & 63;
  const int w = t >> 6;                  // 0..7
  const int lane16 = l & 15;
  const int quad = l >> 4;
  const int jb = blockIdx.x;             // 0..7 -> strips jb and 15-jb
  const int h = blockIdx.y, b = blockIdx.z;
  const int kv = h >> 2;

  // staging geometry (512 threads):
  // K tile 64x128: issue i covers rows i*32 + (t>>4), 16B seg t&15
  // V tile 128x64: issue i covers rows i*64 + (t>>3), 16B seg t&7
  const int krow = t >> 4, kseg = t & 15;
  const int vrow = t >> 3, vseg = t & 7;
  const int kswz = (kseg ^ (krow & 7)) * 8;   // swizzled col (shorts)
  const int vswz = (vseg ^ (vrow & 7)) * 8;

  const short* kbaseptr = kg + ((size_t)(b * 2048)) * 512 + kv * 128;
  const short* vbaseptr = vtg + ((size_t)(b * 512 + kv * 128)) * 2048;

  const float SC = 0.08838834764831845f * 1.4426950408889634f; // rsqrt(128)*log2e
  const f32x4 zero = {0.f, 0.f, 0.f, 0.f};
  const int swz = (lane16 & 7) << 3;     // frag-read swizzle (shorts)

  uint4 kr0, kr1, vr0, vr1;
#define LOADT(KB)                                                             \
  do {                                                                        \
    kr0 = *(const uint4*)(kbaseptr + (size_t)((KB) + krow) * 512 + kseg * 8); \
    kr1 = *(const uint4*)(kbaseptr + (size_t)((KB) + 32 + krow) * 512 + kseg * 8); \
    vr0 = *(const uint4*)(vbaseptr + (size_t)(vrow) * 2048 + (KB) + vseg * 8);     \
    vr1 = *(const uint4*)(vbaseptr + (size_t)(64 + vrow) * 2048 + (KB) + vseg * 8);\
  } while (0)
#define WRITET()                                                              \
  do {                                                                        \
    *(uint4*)&Ksm[krow * 128 + kswz] = kr0;                                   \
    *(uint4*)&Ksm[(32 + krow) * 128 + kswz] = kr1;                            \
    *(uint4*)&Vsm[vrow * 64 + vswz] = vr0;                                    \
    *(uint4*)&Vsm[(64 + vrow) * 64 + vswz] = vr1;                             \
  } while (0)

  for (int sp2 = 0; sp2 < 2; ++sp2) {
    const int jj = sp2 ? (15 - jb) : jb;
    const int qb0 = jj * 128;
    const int qw0 = qb0 + w * 16;
    const int qmaxw = qw0 + 15;
    const int ntl = 2 * jj + 2;          // k-tiles this strip

    // Q B-fragments: lane holds Q[q=lane16][d=kk*32+quad*8+j]
    s16x8 qf[4];
    {
      const short* qrow =
          qg + ((size_t)(b * 2048 + qw0 + lane16)) * 2048 + h * 128 + quad * 8;
#pragma unroll
      for (int kk = 0; kk < 4; ++kk) qf[kk] = *(const s16x8*)(qrow + kk * 32);
    }

    f32x4 o[8];
#pragma unroll
    for (int i = 0; i < 8; ++i) o[i] = zero;
    float m_i = NEGH, l_i = 0.f;

    // prologue: stage tile 0
    LOADT(0);
    WRITET();

    for (int tl = 0; tl < ntl; ++tl) {
      __syncthreads();                   // staged tile visible
      const int kbase = tl * 64;
      if (tl + 1 < ntl) LOADT((tl + 1) * 64);   // issue; flies under compute

      if (kbase <= qmaxw) {              // wave-uniform causal skip
        // St = K_tile(64x128) * Q^T: C col=q=lane16, row=key=quad*4+r
        f32x4 st[4];
#pragma unroll
        for (int mt = 0; mt < 4; ++mt) st[mt] = zero;
#pragma unroll
        for (int mt = 0; mt < 4; ++mt) {
          const int rb = (mt * 16 + lane16) * 128;
#pragma unroll
          for (int kk = 0; kk < 4; ++kk) {
            const s16x8 a = *(const s16x8*)&Ksm[rb + ((kk * 32 + quad * 8) ^ swz)];
            st[mt] = __builtin_amdgcn_mfma_f32_16x16x32_bf16(a, qf[kk], st[mt], 0, 0, 0);
          }
        }

        // online softmax (folded scale*log2e); masks finite -1e30
        const bool maskt = (kbase + 63 > qw0);
        const int qabs = qw0 + lane16;
        float tl_ = NEGH;
#pragma unroll
        for (int mt = 0; mt < 4; ++mt)
#pragma unroll
          for (int r = 0; r < 4; ++r) {
            float xx = st[mt][r] * SC;
            if (maskt && (kbase + mt * 16 + quad * 4 + r) > qabs) xx = NEGH;
            st[mt][r] = xx;
            tl_ = fmaxf(tl_, xx);
          }
        tl_ = fmaxf(tl_, __shfl_xor(tl_, 16));
        tl_ = fmaxf(tl_, __shfl_xor(tl_, 32));
        const float mnew = fmaxf(m_i, tl_);
        const float alpha = exp2f(m_i - mnew);
        float rs = 0.f;
#pragma unroll
        for (int mt = 0; mt < 4; ++mt) {
          const float p0 = exp2f(st[mt][0] - mnew);
          const float p1 = exp2f(st[mt][1] - mnew);
          const float p2 = exp2f(st[mt][2] - mnew);
          const float p3 = exp2f(st[mt][3] - mnew);
          rs += (p0 + p1) + (p2 + p3);
          s16x4 pk = { f2bf(p0), f2bf(p1), f2bf(p2), f2bf(p3) };
          *(s16x4*)&Psm[(w * 16 + lane16) * 64 + ((mt * 16 + quad * 4) ^ swz)] = pk;
        }
        rs += __shfl_xor(rs, 16);
        rs += __shfl_xor(rs, 32);
        l_i = l_i * alpha + rs;
        m_i = mnew;

        // rescale O (O rows are q = quad*4+r; alpha lives at lane16=q)
#pragma unroll
        for (int r = 0; r < 4; ++r) {
          const float ar = __shfl(alpha, quad * 4 + r);
#pragma unroll
          for (int ntd = 0; ntd < 8; ++ntd) o[ntd][r] *= ar;
        }

        // PV: O[q][d] += P[q][key] * Vt[d][key]   (wave-private Psm rows)
        const int prb = (w * 16 + lane16) * 64;
#pragma unroll
        for (int kk = 0; kk < 2; ++kk) {
          const s16x8 pf = *(const s16x8*)&Psm[prb + ((kk * 32 + quad * 8) ^ swz)];
#pragma unroll
          for (int ntd = 0; ntd < 8; ++ntd) {
            const s16x8 vf =
                *(const s16x8*)&Vsm[(ntd * 16 + lane16) * 64 + ((kk * 32 + quad * 8) ^ swz)];
            o[ntd] = __builtin_amdgcn_mfma_f32_16x16x32_bf16(pf, vf, o[ntd], 0, 0, 0);
          }
        }
      }

      __syncthreads();                   // everyone done reading this tile
      if (tl + 1 < ntl) WRITET();        // stage next tile (single-buffered)
    }

    // normalize and store: O row q = quad*4+r, col d = ntd*16+lane16
#pragma unroll
    for (int r = 0; r < 4; ++r) {
      const float lr = __shfl(l_i, quad * 4 + r);
      const float inv = 1.f / lr;
      const size_t base =
          ((size_t)(b * 2048 + qw0 + quad * 4 + r)) * 2048 + h * 128 + lane16;
#pragma unroll
      for (int ntd = 0; ntd < 8; ++ntd) og[base + ntd * 16] = f2bf(o[ntd][r] * inv);
    }
  }
#undef LOADT
#undef WRITET
}

// ---------------------------------------------------------------------------
extern "C" void kernel_launch(void* const* d_in, const int* in_sizes, int n_in,
                              void* d_out, int out_size, void* d_ws,
                              size_t ws_size, hipStream_t stream)
{
  const float* x  = (const float*)d_in[0];
  const float* wq = (const float*)d_in[1];
  const float* bq = (const float*)d_in[2];
  const float* wk = (const float*)d_in[3];
  const float* bk = (const float*)d_in[4];
  const float* wv = (const float*)d_in[5];
  const float* bv = (const float*)d_in[6];
  const float* wo = (const float*)d_in[7];
  const float* bo = (const float*)d_in[8];
  float* out = (float*)d_out;

  // ws layout (76 MiB used):
  //   xb  @0      32 MiB  [8192][2048] bf16; dead after V-proj -> wob reuses @0
  //   wqb @32MiB   8 MiB  [2048][2048] bf16
  //   wkb @40MiB   2 MiB  [512][2048]  bf16
  //   wvb @42MiB   2 MiB  [512][2048]  bf16
  //   qws @44MiB  32 MiB  [8192][2048] bf16; attention output in place
  // d_out (64 MiB fp32) doubles as scratch for K / Vt (dead before final GEMM):
  //   kws @out+0   8 MiB  [8192][512]  bf16
  //   vtw @out+8M  8 MiB  [b][kv*128][2048] bf16
  char* ws = (char*)d_ws;
  short* xb  = (short*)ws;
  short* wqb = (short*)(ws + (32ull << 20));
  short* wkb = (short*)(ws + (40ull << 20));
  short* wvb = (short*)(ws + (42ull << 20));
  short* qws = (short*)(ws + (44ull << 20));
  short* wob = xb;
  short* kws = (short*)d_out;
  short* vtw = (short*)((char*)d_out + (8ull << 20));

  const dim3 blk(256);
  // fp32 -> bf16 input conversions
  cvt_kernel<<<16384, blk, 0, stream>>>(x,  xb);   // 16.7M elems
  cvt_kernel<<<4096,  blk, 0, stream>>>(wq, wqb);  // 4.19M
  cvt_kernel<<<1024,  blk, 0, stream>>>(wk, wkb);  // 1.05M
  cvt_kernel<<<1024,  blk, 0, stream>>>(wv, wvb);  // 1.05M
  // projections (bf16 MFMA, fp32 bias)
  gemm_bt<<<dim3(16, 64), blk, 0, stream>>>(xb, wqb, bq, qws, 8192, 2048, 2048, 0);
  gemm_bt<<<dim3(4, 64),  blk, 0, stream>>>(xb, wkb, bk, kws, 8192, 512, 2048, 0);
  gemm_bt<<<dim3(4, 64),  blk, 0, stream>>>(xb, wvb, bv, vtw, 8192, 512, 2048, 2);
  // rope (q: nh=16 -> lognh 4; k: nh=4 -> lognh 2); v untouched
  rope_kernel<<<32768, blk, 0, stream>>>(qws, 4);
  rope_kernel<<<8192,  blk, 0, stream>>>(kws, 2);
  // wo conversion into xb's slot (xb dead after V-proj; stream-ordered)
  cvt_kernel<<<4096, blk, 0, stream>>>(wo, wob);   // 4.19M
  // attention (in place on qws; 512-thread blocks, paired strips, balanced)
  attn_kernel<<<dim3(8, 16, 4), dim3(512), 0, stream>>>(qws, kws, vtw, qws);
  // output projection: fp32 C into d_out (kws/vtw dead now)
  gemm_bt<<<dim3(16, 64), blk, 0, stream>>>(qws, wob, bo, out, 8192, 2048, 2048, 1);
}

// Round 3
// 565.218 us; speedup vs baseline: 1.6707x; 1.1047x over previous
//
#include <hip/hip_runtime.h>
#include <stdint.h>
#include <math.h>

typedef __attribute__((ext_vector_type(8))) short s16x8;
typedef __attribute__((ext_vector_type(4))) short s16x4;
typedef __attribute__((ext_vector_type(4))) float f32x4;

#define NEGH (-1.0e30f)

__device__ __forceinline__ short f2bf(float f) {
  union { float f; unsigned int i; } c; c.f = f;
  unsigned int lsb = (c.i >> 16) & 1u;
  c.i += 0x7fffu + lsb;
  return (short)(c.i >> 16);
}
__device__ __forceinline__ float bf2f(short u) {
  union { unsigned int i; float f; } c;
  c.i = ((unsigned int)(unsigned short)u) << 16;
  return c.f;
}

// async global->LDS, 16B per lane. LDS dest must be wave-uniform base + lane*16.
#define GLOAD_LDS16(gp, lp)                                                  \
  __builtin_amdgcn_global_load_lds(                                          \
      (__attribute__((address_space(1))) void*)(void*)(gp),                  \
      (__attribute__((address_space(3))) void*)(lp), 16, 0, 0)

// ---------------------------------------------------------------------------
// fp32 -> bf16 conversion, 4 elements/thread. n must be divisible by 1024.
// ---------------------------------------------------------------------------
__global__ __launch_bounds__(256) void cvt_kernel(const float* __restrict__ in,
                                                  short* __restrict__ out)
{
  const size_t i = ((size_t)blockIdx.x * 256 + threadIdx.x) * 4;
  const float4 v = *(const float4*)(in + i);
  s16x4 o = { f2bf(v.x), f2bf(v.y), f2bf(v.z), f2bf(v.w) };
  *(s16x4*)(out + i) = o;
}

// ---------------------------------------------------------------------------
// GEMM (small-N): C[M,N] = A[M,K] * W[N,K]^T + bias[N]. 128x128 tile, BK=64,
// 256 threads. omode: 0 = bf16 C; 1 = fp32 C; 2 = bf16 scatter C^T (vt).
// ---------------------------------------------------------------------------
__global__ __launch_bounds__(256) void gemm_bt(
    const short* __restrict__ A, const short* __restrict__ W,
    const float* __restrict__ bias, void* __restrict__ C,
    int M, int N, int K, int omode)
{
  __shared__ __align__(16) short As[128 * 64];
  __shared__ __align__(16) short Bs[128 * 64];

  const int t = threadIdx.x;
  const int l = t & 63;
  const int w = t >> 6;
  const int lane16 = l & 15;
  const int quad = l >> 4;
  const int wm = w >> 1, wn = w & 1;
  const int mb0 = blockIdx.y * 128;
  const int nb0 = blockIdx.x * 128;

  const f32x4 zero = {0.f, 0.f, 0.f, 0.f};
  f32x4 acc[4][4];
#pragma unroll
  for (int i = 0; i < 4; ++i)
#pragma unroll
    for (int j = 0; j < 4; ++j) acc[i][j] = zero;

  const int sr = t >> 3;
  const int sp = t & 7;
  const short* Ag = A + (size_t)(mb0 + sr) * K + sp * 8;
  const short* Wg = W + (size_t)(nb0 + sr) * K + sp * 8;
  short* Al = As + t * 8;
  short* Bl = Bs + t * 8;

  const int nkt = K >> 6;
  for (int kt = 0; kt < nkt; ++kt) {
    __syncthreads();
    const int kof = kt * 64;
#pragma unroll
    for (int it = 0; it < 4; ++it) {
      GLOAD_LDS16(Ag + kof + (size_t)(it * 32) * K, Al + it * 2048);
      GLOAD_LDS16(Wg + kof + (size_t)(it * 32) * K, Bl + it * 2048);
    }
    __syncthreads();
#pragma unroll
    for (int kk = 0; kk < 2; ++kk) {
      s16x8 af[4], bf[4];
#pragma unroll
      for (int mi = 0; mi < 4; ++mi)
        af[mi] = *(const s16x8*)&As[(wm * 64 + mi * 16 + lane16) * 64 +
                                    kk * 32 + quad * 8];
#pragma unroll
      for (int ni = 0; ni < 4; ++ni)
        bf[ni] = *(const s16x8*)&Bs[(wn * 64 + ni * 16 + lane16) * 64 +
                                    kk * 32 + quad * 8];
#pragma unroll
      for (int mi = 0; mi < 4; ++mi)
#pragma unroll
        for (int ni = 0; ni < 4; ++ni)
          acc[mi][ni] = __builtin_amdgcn_mfma_f32_16x16x32_bf16(
              af[mi], bf[ni], acc[mi][ni], 0, 0, 0);
    }
  }

#pragma unroll
  for (int ni = 0; ni < 4; ++ni) {
    const int n = nb0 + wn * 64 + ni * 16 + lane16;
    const float bv = bias[n];
#pragma unroll
    for (int mi = 0; mi < 4; ++mi) {
      const int m0 = mb0 + wm * 64 + mi * 16 + quad * 4;
#pragma unroll
      for (int r = 0; r < 4; ++r) {
        const int m = m0 + r;
        const float v = acc[mi][ni][r] + bv;
        if (omode == 0) {
          ((short*)C)[(size_t)m * N + n] = f2bf(v);
        } else if (omode == 1) {
          ((float*)C)[(size_t)m * N + n] = v;
        } else {
          ((short*)C)[((size_t)(m >> 11) * N + n) * 2048 + (m & 2047)] = f2bf(v);
        }
      }
    }
  }
}

// ---------------------------------------------------------------------------
// GEMM (big): 256x256 tile, BK=64, 512 threads = 8 waves (2M x 4N), 8-phase
// schedule (T2+T3+T4+T5). LDS 128 KiB: A,B double-buffered, each buffer
// [kk(2)][row(256)][32] (k-half slices are contiguous 16KB half-tiles -> 2
// global_load_lds issues each). Bank-conflict swizzle: chunk ^= (row>>1)&3,
// applied on the GLOBAL source (linear LDS dest) and on ds_read addr.
// Pipeline: 1 half-tile issued per phase, 14 loads in flight, vmcnt(10) at
// even-phase ends (never 0). Raw s_barrier + explicit waitcnts.
// Per K-tile: 4 phases {kk0/mi0-3, kk0/mi4-7, kk1/mi0-3, kk1/mi4-7},
// 16 MFMA each; B frags (4) read on odd phases, reused on even.
// Requires M%256==0, N%256==0, K%128==0. omode: 0 = bf16 C; 1 = fp32 C.
// ---------------------------------------------------------------------------
__global__ __launch_bounds__(512, 2) void gemm256_bt(
    const short* __restrict__ A, const short* __restrict__ W,
    const float* __restrict__ bias, void* __restrict__ C,
    int M, int N, int K, int omode)
{
  __shared__ __align__(16) short Asm[2 * 16384];   // [buf][kk][row][32]
  __shared__ __align__(16) short Bsm[2 * 16384];

  const int t = threadIdx.x;
  const int l = t & 63;
  const int w = t >> 6;                // 0..7
  const int lane16 = l & 15;
  const int quad = l >> 4;
  const int wm = w >> 2;               // 0..1
  const int wn = w & 3;                // 0..3
  const int mb0 = blockIdx.y * 256;
  const int nb0 = blockIdx.x * 256;

  const f32x4 zero = {0.f, 0.f, 0.f, 0.f};
  f32x4 acc[8][4];
#pragma unroll
  for (int i = 0; i < 8; ++i)
#pragma unroll
    for (int j = 0; j < 4; ++j) acc[i][j] = zero;

  // staging: thread t covers row j*128 + (t>>2), dest chunk t&3 (of 4 per row),
  // source chunk pre-swizzled so LDS[row][c] = global[row][c ^ ((row>>1)&3)].
  const int srow = t >> 2;                       // 0..127
  const int scs = (t & 3) ^ ((t >> 3) & 3);      // (row>>1)&3 == (t>>3)&3
  const short* Ag = A + (size_t)(mb0 + srow) * K + scs * 8;
  const short* Wg = W + (size_t)(nb0 + srow) * K + scs * 8;
  const size_t rstep = (size_t)128 * K;          // issue j=1: +128 rows

#define STAGE_A(b, kt, kh)                                                    \
  do {                                                                        \
    const size_t ko_ = (size_t)(kt) * 64 + (kh) * 32;                         \
    GLOAD_LDS16(Ag + ko_,         Asm + (b) * 16384 + (kh) * 8192 + t * 8);   \
    GLOAD_LDS16(Ag + ko_ + rstep, Asm + (b) * 16384 + (kh) * 8192 + 4096 + t * 8); \
  } while (0)
#define STAGE_B(b, kt, kh)                                                    \
  do {                                                                        \
    const size_t ko_ = (size_t)(kt) * 64 + (kh) * 32;                         \
    GLOAD_LDS16(Wg + ko_,         Bsm + (b) * 16384 + (kh) * 8192 + t * 8);   \
    GLOAD_LDS16(Wg + ko_ + rstep, Bsm + (b) * 16384 + (kh) * 8192 + 4096 + t * 8); \
  } while (0)

  s16x8 bfr[4];

#define DO_PHASE(BUF, KK, MG, READB, STAGE_STMT, DO_VM)                       \
  {                                                                           \
    const short* Abase = Asm + (BUF) * 16384 + (KK) * 8192;                   \
    const short* Bbase = Bsm + (BUF) * 16384 + (KK) * 8192;                   \
    if (READB) {                                                              \
      _Pragma("unroll")                                                       \
      for (int ni = 0; ni < 4; ++ni) {                                        \
        const int nr = wn * 64 + ni * 16 + lane16;                            \
        bfr[ni] = *(const s16x8*)(Bbase + nr * 32 +                           \
                                  ((quad ^ ((nr >> 1) & 3)) << 3));           \
      }                                                                       \
    }                                                                         \
    s16x8 afr[4];                                                             \
    _Pragma("unroll")                                                         \
    for (int mi2 = 0; mi2 < 4; ++mi2) {                                       \
      const int mr = wm * 128 + (MG) * 64 + mi2 * 16 + lane16;                \
      afr[mi2] = *(const s16x8*)(Abase + mr * 32 +                            \
                                 ((quad ^ ((mr >> 1) & 3)) << 3));            \
    }                                                                         \
    STAGE_STMT;                                                               \
    __builtin_amdgcn_s_barrier();                                             \
    asm volatile("s_waitcnt lgkmcnt(0)" ::: "memory");                        \
    __builtin_amdgcn_sched_barrier(0);                                        \
    __builtin_amdgcn_s_setprio(1);                                            \
    _Pragma("unroll")                                                         \
    for (int mi2 = 0; mi2 < 4; ++mi2)                                         \
      _Pragma("unroll")                                                       \
      for (int ni = 0; ni < 4; ++ni)                                          \
        acc[(MG) * 4 + mi2][ni] = __builtin_amdgcn_mfma_f32_16x16x32_bf16(    \
            afr[mi2], bfr[ni], acc[(MG) * 4 + mi2][ni], 0, 0, 0);             \
    __builtin_amdgcn_s_setprio(0);                                            \
    if (DO_VM) {                                                              \
      asm volatile("s_waitcnt vmcnt(10)" ::: "memory");                       \
      __builtin_amdgcn_sched_barrier(0);                                      \
    }                                                                         \
    __builtin_amdgcn_s_barrier();                                             \
  }

  const int NT = K >> 6;               // K-tiles (even; >= 2)

  // prologue: stage t0 fully + t1 {Bkh0, Akh0, Bkh1} (t1.Akh1 issued at P1).
  STAGE_B(0, 0, 0); STAGE_A(0, 0, 0); STAGE_B(0, 0, 1); STAGE_A(0, 0, 1);
  STAGE_B(1, 1, 0); STAGE_A(1, 1, 0); STAGE_B(1, 1, 1);
  asm volatile("s_waitcnt vmcnt(10)" ::: "memory");
  __builtin_amdgcn_sched_barrier(0);
  __builtin_amdgcn_s_barrier();

  for (int i2 = 0; i2 < NT; i2 += 2) {
    const int tp1 = (i2 + 1 < NT) ? i2 + 1 : NT - 1;
    const int tp2 = (i2 + 2 < NT) ? i2 + 2 : NT - 1;
    const int tp3 = (i2 + 3 < NT) ? i2 + 3 : NT - 1;
    DO_PHASE(0, 0, 0, true,  STAGE_A(1, tp1, 1), false)   // P1
    DO_PHASE(0, 0, 1, false, STAGE_B(0, tp2, 0), true)    // P2
    DO_PHASE(0, 1, 0, true,  STAGE_A(0, tp2, 0), false)   // P3
    DO_PHASE(0, 1, 1, false, STAGE_B(0, tp2, 1), true)    // P4
    DO_PHASE(1, 0, 0, true,  STAGE_A(0, tp2, 1), false)   // P5
    DO_PHASE(1, 0, 1, false, STAGE_B(1, tp3, 0), true)    // P6
    DO_PHASE(1, 1, 0, true,  STAGE_A(1, tp3, 0), false)   // P7
    DO_PHASE(1, 1, 1, false, STAGE_B(1, tp3, 1), true)    // P8
  }

  // epilogue: C/D layout col=lane&15 (n), row=quad*4+reg (m)
#pragma unroll
  for (int ni = 0; ni < 4; ++ni) {
    const int n = nb0 + wn * 64 + ni * 16 + lane16;
    const float bv = bias[n];
#pragma unroll
    for (int mi = 0; mi < 8; ++mi) {
      const int m0 = mb0 + wm * 128 + mi * 16 + quad * 4;
#pragma unroll
      for (int r = 0; r < 4; ++r) {
        const float v = acc[mi][ni][r] + bv;
        if (omode == 0) ((short*)C)[(size_t)(m0 + r) * N + n] = f2bf(v);
        else            ((float*)C)[(size_t)(m0 + r) * N + n] = v;
      }
    }
  }
#undef DO_PHASE
#undef STAGE_A
#undef STAGE_B
}

// ---------------------------------------------------------------------------
// RoPE in place on bf16 buf[row][head*128 + d], pairs (d, d+64), pos = row%2048.
// ---------------------------------------------------------------------------
__global__ __launch_bounds__(256) void rope_kernel(short* __restrict__ buf,
                                                   int lognh)
{
  const int idx = blockIdx.x * 256 + threadIdx.x;
  const int d = idx & 63;
  const int rest = idx >> 6;
  const int row = rest >> lognh;
  const int pos = row & 2047;
  const float fr = (float)pos * exp2f((float)d * -0.20762050593048584f);
  float sn, cs;
  sincosf(fr, &sn, &cs);
  const size_t base = (size_t)rest * 128 + d;
  const float lo = bf2f(buf[base]);
  const float hi = bf2f(buf[base + 64]);
  buf[base]      = f2bf(lo * cs - hi * sn);
  buf[base + 64] = f2bf(hi * cs + lo * sn);
}

// ---------------------------------------------------------------------------
// Flash attention, causal, GQA (kv = h>>2). LDS-staged + latency-overlapped.
// (unchanged from r2; see comments there)
// ---------------------------------------------------------------------------
__global__ __launch_bounds__(512, 4) void attn_kernel(
    const short* __restrict__ qg, const short* __restrict__ kg,
    const short* __restrict__ vtg, short* __restrict__ og)
{
  __shared__ __align__(16) short Ksm[64 * 128];   // [key][d], swizzled
  __shared__ __align__(16) short Vsm[128 * 64];   // [d][key], swizzled
  __shared__ __align__(16) short Psm[128 * 64];   // [q][key], swizzled

  const int t = threadIdx.x;
  const int l = t & 63;
  const int w = t >> 6;
  const int lane16 = l & 15;
  const int quad = l >> 4;
  const int jb = blockIdx.x;
  const int h = blockIdx.y, b = blockIdx.z;
  const int kv = h >> 2;

  const int krow = t >> 4, kseg = t & 15;
  const int vrow = t >> 3, vseg = t & 7;
  const int kswz = (kseg ^ (krow & 7)) * 8;
  const int vswz = (vseg ^ (vrow & 7)) * 8;

  const short* kbaseptr = kg + ((size_t)(b * 2048)) * 512 + kv * 128;
  const short* vbaseptr = vtg + ((size_t)(b * 512 + kv * 128)) * 2048;

  const float SC = 0.08838834764831845f * 1.4426950408889634f;
  const f32x4 zero = {0.f, 0.f, 0.f, 0.f};
  const int swz = (lane16 & 7) << 3;

  uint4 kr0, kr1, vr0, vr1;
#define LOADT(KB)                                                             \
  do {                                                                        \
    kr0 = *(const uint4*)(kbaseptr + (size_t)((KB) + krow) * 512 + kseg * 8); \
    kr1 = *(const uint4*)(kbaseptr + (size_t)((KB) + 32 + krow) * 512 + kseg * 8); \
    vr0 = *(const uint4*)(vbaseptr + (size_t)(vrow) * 2048 + (KB) + vseg * 8);     \
    vr1 = *(const uint4*)(vbaseptr + (size_t)(64 + vrow) * 2048 + (KB) + vseg * 8);\
  } while (0)
#define WRITET()                                                              \
  do {                                                                        \
    *(uint4*)&Ksm[krow * 128 + kswz] = kr0;                                   \
    *(uint4*)&Ksm[(32 + krow) * 128 + kswz] = kr1;                            \
    *(uint4*)&Vsm[vrow * 64 + vswz] = vr0;                                    \
    *(uint4*)&Vsm[(64 + vrow) * 64 + vswz] = vr1;                             \
  } while (0)

  for (int sp2 = 0; sp2 < 2; ++sp2) {
    const int jj = sp2 ? (15 - jb) : jb;
    const int qb0 = jj * 128;
    const int qw0 = qb0 + w * 16;
    const int qmaxw = qw0 + 15;
    const int ntl = 2 * jj + 2;

    s16x8 qf[4];
    {
      const short* qrow =
          qg + ((size_t)(b * 2048 + qw0 + lane16)) * 2048 + h * 128 + quad * 8;
#pragma unroll
      for (int kk = 0; kk < 4; ++kk) qf[kk] = *(const s16x8*)(qrow + kk * 32);
    }

    f32x4 o[8];
#pragma unroll
    for (int i = 0; i < 8; ++i) o[i] = zero;
    float m_i = NEGH, l_i = 0.f;

    LOADT(0);
    WRITET();

    for (int tl = 0; tl < ntl; ++tl) {
      __syncthreads();
      const int kbase = tl * 64;
      if (tl + 1 < ntl) LOADT((tl + 1) * 64);

      if (kbase <= qmaxw) {
        f32x4 st[4];
#pragma unroll
        for (int mt = 0; mt < 4; ++mt) st[mt] = zero;
#pragma unroll
        for (int mt = 0; mt < 4; ++mt) {
          const int rb = (mt * 16 + lane16) * 128;
#pragma unroll
          for (int kk = 0; kk < 4; ++kk) {
            const s16x8 a = *(const s16x8*)&Ksm[rb + ((kk * 32 + quad * 8) ^ swz)];
            st[mt] = __builtin_amdgcn_mfma_f32_16x16x32_bf16(a, qf[kk], st[mt], 0, 0, 0);
          }
        }

        const bool maskt = (kbase + 63 > qw0);
        const int qabs = qw0 + lane16;
        float tl_ = NEGH;
#pragma unroll
        for (int mt = 0; mt < 4; ++mt)
#pragma unroll
          for (int r = 0; r < 4; ++r) {
            float xx = st[mt][r] * SC;
            if (maskt && (kbase + mt * 16 + quad * 4 + r) > qabs) xx = NEGH;
            st[mt][r] = xx;
            tl_ = fmaxf(tl_, xx);
          }
        tl_ = fmaxf(tl_, __shfl_xor(tl_, 16));
        tl_ = fmaxf(tl_, __shfl_xor(tl_, 32));
        const float mnew = fmaxf(m_i, tl_);
        const float alpha = exp2f(m_i - mnew);
        float rs = 0.f;
#pragma unroll
        for (int mt = 0; mt < 4; ++mt) {
          const float p0 = exp2f(st[mt][0] - mnew);
          const float p1 = exp2f(st[mt][1] - mnew);
          const float p2 = exp2f(st[mt][2] - mnew);
          const float p3 = exp2f(st[mt][3] - mnew);
          rs += (p0 + p1) + (p2 + p3);
          s16x4 pk = { f2bf(p0), f2bf(p1), f2bf(p2), f2bf(p3) };
          *(s16x4*)&Psm[(w * 16 + lane16) * 64 + ((mt * 16 + quad * 4) ^ swz)] = pk;
        }
        rs += __shfl_xor(rs, 16);
        rs += __shfl_xor(rs, 32);
        l_i = l_i * alpha + rs;
        m_i = mnew;

#pragma unroll
        for (int r = 0; r < 4; ++r) {
          const float ar = __shfl(alpha, quad * 4 + r);
#pragma unroll
          for (int ntd = 0; ntd < 8; ++ntd) o[ntd][r] *= ar;
        }

        const int prb = (w * 16 + lane16) * 64;
#pragma unroll
        for (int kk = 0; kk < 2; ++kk) {
          const s16x8 pf = *(const s16x8*)&Psm[prb + ((kk * 32 + quad * 8) ^ swz)];
#pragma unroll
          for (int ntd = 0; ntd < 8; ++ntd) {
            const s16x8 vf =
                *(const s16x8*)&Vsm[(ntd * 16 + lane16) * 64 + ((kk * 32 + quad * 8) ^ swz)];
            o[ntd] = __builtin_amdgcn_mfma_f32_16x16x32_bf16(pf, vf, o[ntd], 0, 0, 0);
          }
        }
      }

      __syncthreads();
      if (tl + 1 < ntl) WRITET();
    }

#pragma unroll
    for (int r = 0; r < 4; ++r) {
      const float lr = __shfl(l_i, quad * 4 + r);
      const float inv = 1.f / lr;
      const size_t base =
          ((size_t)(b * 2048 + qw0 + quad * 4 + r)) * 2048 + h * 128 + lane16;
#pragma unroll
      for (int ntd = 0; ntd < 8; ++ntd) og[base + ntd * 16] = f2bf(o[ntd][r] * inv);
    }
  }
#undef LOADT
#undef WRITET
}

// ---------------------------------------------------------------------------
extern "C" void kernel_launch(void* const* d_in, const int* in_sizes, int n_in,
                              void* d_out, int out_size, void* d_ws,
                              size_t ws_size, hipStream_t stream)
{
  const float* x  = (const float*)d_in[0];
  const float* wq = (const float*)d_in[1];
  const float* bq = (const float*)d_in[2];
  const float* wk = (const float*)d_in[3];
  const float* bk = (const float*)d_in[4];
  const float* wv = (const float*)d_in[5];
  const float* bv = (const float*)d_in[6];
  const float* wo = (const float*)d_in[7];
  const float* bo = (const float*)d_in[8];
  float* out = (float*)d_out;

  // ws layout (76 MiB used):
  //   xb  @0      32 MiB  [8192][2048] bf16; dead after V-proj -> wob reuses @0
  //   wqb @32MiB   8 MiB; wkb @40MiB 2 MiB; wvb @42MiB 2 MiB
  //   qws @44MiB  32 MiB  [8192][2048] bf16; attention output in place
  // d_out doubles as scratch: kws @out+0 8 MiB; vtw @out+8M 8 MiB
  char* ws = (char*)d_ws;
  short* xb  = (short*)ws;
  short* wqb = (short*)(ws + (32ull << 20));
  short* wkb = (short*)(ws + (40ull << 20));
  short* wvb = (short*)(ws + (42ull << 20));
  short* qws = (short*)(ws + (44ull << 20));
  short* wob = xb;
  short* kws = (short*)d_out;
  short* vtw = (short*)((char*)d_out + (8ull << 20));

  const dim3 blk(256);
  cvt_kernel<<<16384, blk, 0, stream>>>(x,  xb);
  cvt_kernel<<<4096,  blk, 0, stream>>>(wq, wqb);
  cvt_kernel<<<1024,  blk, 0, stream>>>(wk, wkb);
  cvt_kernel<<<1024,  blk, 0, stream>>>(wv, wvb);
  // projections: big GEMMs on the 256^2 8-phase kernel, K/V on 128^2
  gemm256_bt<<<dim3(8, 32), dim3(512), 0, stream>>>(xb, wqb, bq, qws, 8192, 2048, 2048, 0);
  gemm_bt<<<dim3(4, 64),  blk, 0, stream>>>(xb, wkb, bk, kws, 8192, 512, 2048, 0);
  gemm_bt<<<dim3(4, 64),  blk, 0, stream>>>(xb, wvb, bv, vtw, 8192, 512, 2048, 2);
  rope_kernel<<<32768, blk, 0, stream>>>(qws, 4);
  rope_kernel<<<8192,  blk, 0, stream>>>(kws, 2);
  cvt_kernel<<<4096, blk, 0, stream>>>(wo, wob);
  attn_kernel<<<dim3(8, 16, 4), dim3(512), 0, stream>>>(qws, kws, vtw, qws);
  gemm256_bt<<<dim3(8, 32), dim3(512), 0, stream>>>(qws, wob, bo, out, 8192, 2048, 2048, 1);
}

// Round 4
// 532.796 us; speedup vs baseline: 1.7723x; 1.0609x over previous
//
#include <hip/hip_runtime.h>
#include <stdint.h>
#include <math.h>

typedef __attribute__((ext_vector_type(8))) short s16x8;
typedef __attribute__((ext_vector_type(4))) short s16x4;
typedef __attribute__((ext_vector_type(4))) float f32x4;

#define NEGH (-1.0e30f)

__device__ __forceinline__ short f2bf(float f) {
  union { float f; unsigned int i; } c; c.f = f;
  unsigned int lsb = (c.i >> 16) & 1u;
  c.i += 0x7fffu + lsb;
  return (short)(c.i >> 16);
}
__device__ __forceinline__ float bf2f(short u) {
  union { unsigned int i; float f; } c;
  c.i = ((unsigned int)(unsigned short)u) << 16;
  return c.f;
}

// async global->LDS, 16B per lane. LDS dest must be wave-uniform base + lane*16.
#define GLOAD_LDS16(gp, lp)                                                  \
  __builtin_amdgcn_global_load_lds(                                          \
      (__attribute__((address_space(1))) void*)(void*)(gp),                  \
      (__attribute__((address_space(3))) void*)(lp), 16, 0, 0)

// ---------------------------------------------------------------------------
// fp32 -> bf16 conversion, 4 elements/thread. n must be divisible by 1024.
// ---------------------------------------------------------------------------
__global__ __launch_bounds__(256) void cvt_kernel(const float* __restrict__ in,
                                                  short* __restrict__ out)
{
  const size_t i = ((size_t)blockIdx.x * 256 + threadIdx.x) * 4;
  const float4 v = *(const float4*)(in + i);
  s16x4 o = { f2bf(v.x), f2bf(v.y), f2bf(v.z), f2bf(v.w) };
  *(s16x4*)(out + i) = o;
}

// ---------------------------------------------------------------------------
// GEMM (small-N): C[M,N] = A[M,K] * W[N,K]^T + bias[N]. 128x128 tile, BK=64,
// 256 threads. omode: 0 = bf16 C row-major; 1 = fp32 C row-major;
// 3 = split KV: n<512 -> bf16 C[m*512+n] (bias), n>=512 -> bf16 C2[m*512+n-512]
//     (bias2). 512-boundary is block-uniform (nb0 multiple of 128).
// ---------------------------------------------------------------------------
__global__ __launch_bounds__(256) void gemm_bt(
    const short* __restrict__ A, const short* __restrict__ W,
    const float* __restrict__ bias, const float* __restrict__ bias2,
    void* __restrict__ C, void* __restrict__ C2,
    int M, int N, int K, int omode)
{
  __shared__ __align__(16) short As[128 * 64];
  __shared__ __align__(16) short Bs[128 * 64];

  const int t = threadIdx.x;
  const int l = t & 63;
  const int w = t >> 6;
  const int lane16 = l & 15;
  const int quad = l >> 4;
  const int wm = w >> 1, wn = w & 1;
  const int mb0 = blockIdx.y * 128;
  const int nb0 = blockIdx.x * 128;

  const f32x4 zero = {0.f, 0.f, 0.f, 0.f};
  f32x4 acc[4][4];
#pragma unroll
  for (int i = 0; i < 4; ++i)
#pragma unroll
    for (int j = 0; j < 4; ++j) acc[i][j] = zero;

  const int sr = t >> 3;
  const int sp = t & 7;
  const short* Ag = A + (size_t)(mb0 + sr) * K + sp * 8;
  const short* Wg = W + (size_t)(nb0 + sr) * K + sp * 8;
  short* Al = As + t * 8;
  short* Bl = Bs + t * 8;

  const int nkt = K >> 6;
  for (int kt = 0; kt < nkt; ++kt) {
    __syncthreads();
    const int kof = kt * 64;
#pragma unroll
    for (int it = 0; it < 4; ++it) {
      GLOAD_LDS16(Ag + kof + (size_t)(it * 32) * K, Al + it * 2048);
      GLOAD_LDS16(Wg + kof + (size_t)(it * 32) * K, Bl + it * 2048);
    }
    __syncthreads();
#pragma unroll
    for (int kk = 0; kk < 2; ++kk) {
      s16x8 af[4], bf[4];
#pragma unroll
      for (int mi = 0; mi < 4; ++mi)
        af[mi] = *(const s16x8*)&As[(wm * 64 + mi * 16 + lane16) * 64 +
                                    kk * 32 + quad * 8];
#pragma unroll
      for (int ni = 0; ni < 4; ++ni)
        bf[ni] = *(const s16x8*)&Bs[(wn * 64 + ni * 16 + lane16) * 64 +
                                    kk * 32 + quad * 8];
#pragma unroll
      for (int mi = 0; mi < 4; ++mi)
#pragma unroll
        for (int ni = 0; ni < 4; ++ni)
          acc[mi][ni] = __builtin_amdgcn_mfma_f32_16x16x32_bf16(
              af[mi], bf[ni], acc[mi][ni], 0, 0, 0);
    }
  }

#pragma unroll
  for (int ni = 0; ni < 4; ++ni) {
    const int n = nb0 + wn * 64 + ni * 16 + lane16;
    const float bvx = (omode == 3 && n >= 512) ? bias2[n - 512] : bias[n];
#pragma unroll
    for (int mi = 0; mi < 4; ++mi) {
      const int m0 = mb0 + wm * 64 + mi * 16 + quad * 4;
#pragma unroll
      for (int r = 0; r < 4; ++r) {
        const int m = m0 + r;
        const float v = acc[mi][ni][r] + bvx;
        if (omode == 0) {
          ((short*)C)[(size_t)m * N + n] = f2bf(v);
        } else if (omode == 1) {
          ((float*)C)[(size_t)m * N + n] = v;
        } else {
          if (n < 512) ((short*)C)[(size_t)m * 512 + n] = f2bf(v);
          else         ((short*)C2)[(size_t)m * 512 + (n - 512)] = f2bf(v);
        }
      }
    }
  }
}

// ---------------------------------------------------------------------------
// GEMM (big): 256x256 tile, BK=64, 512 threads = 8 waves (2M x 4N), 8-phase
// schedule (T2+T3+T4+T5). See r3 comments. omode: 0 = bf16 C; 1 = fp32 C.
// ---------------------------------------------------------------------------
__global__ __launch_bounds__(512, 2) void gemm256_bt(
    const short* __restrict__ A, const short* __restrict__ W,
    const float* __restrict__ bias, void* __restrict__ C,
    int M, int N, int K, int omode)
{
  __shared__ __align__(16) short Asm[2 * 16384];   // [buf][kk][row][32]
  __shared__ __align__(16) short Bsm[2 * 16384];

  const int t = threadIdx.x;
  const int l = t & 63;
  const int w = t >> 6;                // 0..7
  const int lane16 = l & 15;
  const int quad = l >> 4;
  const int wm = w >> 2;               // 0..1
  const int wn = w & 3;                // 0..3
  const int mb0 = blockIdx.y * 256;
  const int nb0 = blockIdx.x * 256;

  const f32x4 zero = {0.f, 0.f, 0.f, 0.f};
  f32x4 acc[8][4];
#pragma unroll
  for (int i = 0; i < 8; ++i)
#pragma unroll
    for (int j = 0; j < 4; ++j) acc[i][j] = zero;

  const int srow = t >> 2;                       // 0..127
  const int scs = (t & 3) ^ ((t >> 3) & 3);      // pre-swizzled source chunk
  const short* Ag = A + (size_t)(mb0 + srow) * K + scs * 8;
  const short* Wg = W + (size_t)(nb0 + srow) * K + scs * 8;
  const size_t rstep = (size_t)128 * K;

#define STAGE_A(b, kt, kh)                                                    \
  do {                                                                        \
    const size_t ko_ = (size_t)(kt) * 64 + (kh) * 32;                         \
    GLOAD_LDS16(Ag + ko_,         Asm + (b) * 16384 + (kh) * 8192 + t * 8);   \
    GLOAD_LDS16(Ag + ko_ + rstep, Asm + (b) * 16384 + (kh) * 8192 + 4096 + t * 8); \
  } while (0)
#define STAGE_B(b, kt, kh)                                                    \
  do {                                                                        \
    const size_t ko_ = (size_t)(kt) * 64 + (kh) * 32;                         \
    GLOAD_LDS16(Wg + ko_,         Bsm + (b) * 16384 + (kh) * 8192 + t * 8);   \
    GLOAD_LDS16(Wg + ko_ + rstep, Bsm + (b) * 16384 + (kh) * 8192 + 4096 + t * 8); \
  } while (0)

  s16x8 bfr[4];

#define DO_PHASE(BUF, KK, MG, READB, STAGE_STMT, DO_VM)                       \
  {                                                                           \
    const short* Abase = Asm + (BUF) * 16384 + (KK) * 8192;                   \
    const short* Bbase = Bsm + (BUF) * 16384 + (KK) * 8192;                   \
    if (READB) {                                                              \
      _Pragma("unroll")                                                       \
      for (int ni = 0; ni < 4; ++ni) {                                        \
        const int nr = wn * 64 + ni * 16 + lane16;                            \
        bfr[ni] = *(const s16x8*)(Bbase + nr * 32 +                           \
                                  ((quad ^ ((nr >> 1) & 3)) << 3));           \
      }                                                                       \
    }                                                                         \
    s16x8 afr[4];                                                             \
    _Pragma("unroll")                                                         \
    for (int mi2 = 0; mi2 < 4; ++mi2) {                                       \
      const int mr = wm * 128 + (MG) * 64 + mi2 * 16 + lane16;                \
      afr[mi2] = *(const s16x8*)(Abase + mr * 32 +                            \
                                 ((quad ^ ((mr >> 1) & 3)) << 3));            \
    }                                                                         \
    STAGE_STMT;                                                               \
    __builtin_amdgcn_s_barrier();                                             \
    asm volatile("s_waitcnt lgkmcnt(0)" ::: "memory");                        \
    __builtin_amdgcn_sched_barrier(0);                                        \
    __builtin_amdgcn_s_setprio(1);                                            \
    _Pragma("unroll")                                                         \
    for (int mi2 = 0; mi2 < 4; ++mi2)                                         \
      _Pragma("unroll")                                                       \
      for (int ni = 0; ni < 4; ++ni)                                          \
        acc[(MG) * 4 + mi2][ni] = __builtin_amdgcn_mfma_f32_16x16x32_bf16(    \
            afr[mi2], bfr[ni], acc[(MG) * 4 + mi2][ni], 0, 0, 0);             \
    __builtin_amdgcn_s_setprio(0);                                            \
    if (DO_VM) {                                                              \
      asm volatile("s_waitcnt vmcnt(10)" ::: "memory");                       \
      __builtin_amdgcn_sched_barrier(0);                                      \
    }                                                                         \
    __builtin_amdgcn_s_barrier();                                             \
  }

  const int NT = K >> 6;               // K-tiles (even; >= 2)

  STAGE_B(0, 0, 0); STAGE_A(0, 0, 0); STAGE_B(0, 0, 1); STAGE_A(0, 0, 1);
  STAGE_B(1, 1, 0); STAGE_A(1, 1, 0); STAGE_B(1, 1, 1);
  asm volatile("s_waitcnt vmcnt(10)" ::: "memory");
  __builtin_amdgcn_sched_barrier(0);
  __builtin_amdgcn_s_barrier();

  for (int i2 = 0; i2 < NT; i2 += 2) {
    const int tp1 = (i2 + 1 < NT) ? i2 + 1 : NT - 1;
    const int tp2 = (i2 + 2 < NT) ? i2 + 2 : NT - 1;
    const int tp3 = (i2 + 3 < NT) ? i2 + 3 : NT - 1;
    DO_PHASE(0, 0, 0, true,  STAGE_A(1, tp1, 1), false)   // P1
    DO_PHASE(0, 0, 1, false, STAGE_B(0, tp2, 0), true)    // P2
    DO_PHASE(0, 1, 0, true,  STAGE_A(0, tp2, 0), false)   // P3
    DO_PHASE(0, 1, 1, false, STAGE_B(0, tp2, 1), true)    // P4
    DO_PHASE(1, 0, 0, true,  STAGE_A(0, tp2, 1), false)   // P5
    DO_PHASE(1, 0, 1, false, STAGE_B(1, tp3, 0), true)    // P6
    DO_PHASE(1, 1, 0, true,  STAGE_A(1, tp3, 0), false)   // P7
    DO_PHASE(1, 1, 1, false, STAGE_B(1, tp3, 1), true)    // P8
  }

#pragma unroll
  for (int ni = 0; ni < 4; ++ni) {
    const int n = nb0 + wn * 64 + ni * 16 + lane16;
    const float bv = bias[n];
#pragma unroll
    for (int mi = 0; mi < 8; ++mi) {
      const int m0 = mb0 + wm * 128 + mi * 16 + quad * 4;
#pragma unroll
      for (int r = 0; r < 4; ++r) {
        const float v = acc[mi][ni][r] + bv;
        if (omode == 0) ((short*)C)[(size_t)(m0 + r) * N + n] = f2bf(v);
        else            ((float*)C)[(size_t)(m0 + r) * N + n] = v;
      }
    }
  }
#undef DO_PHASE
#undef STAGE_A
#undef STAGE_B
}

// ---------------------------------------------------------------------------
// RoPE cos/sin table: tab[pos*64 + d] = {cos, sin}(pos * invfreq(d)).
// 2048*64 entries; computed once (heads share angles; old rope recomputed 16x).
// ---------------------------------------------------------------------------
__global__ __launch_bounds__(256) void rope_tab_kernel(float2* __restrict__ tab)
{
  const int i = blockIdx.x * 256 + threadIdx.x;    // 131072
  const int pos = i >> 6, d = i & 63;
  const float fr = (float)pos * exp2f((float)d * -0.20762050593048584f);
  float sn, cs;
  sincosf(fr, &sn, &cs);
  tab[i] = make_float2(cs, sn);
}

// ---------------------------------------------------------------------------
// RoPE in place on bf16 buf[row][head*128 + d], pairs (d, d+64), pos = row%2048.
// ---------------------------------------------------------------------------
__global__ __launch_bounds__(256) void rope_kernel(short* __restrict__ buf,
                                                   int lognh,
                                                   const float2* __restrict__ tab)
{
  const int idx = blockIdx.x * 256 + threadIdx.x;
  const int d = idx & 63;
  const int rest = idx >> 6;            // row*nh + h
  const int row = rest >> lognh;
  const int pos = row & 2047;
  const float2 cssn = tab[(pos << 6) | d];
  const float cs = cssn.x, sn = cssn.y;
  const size_t base = (size_t)rest * 128 + d;
  const float lo = bf2f(buf[base]);
  const float hi = bf2f(buf[base + 64]);
  buf[base]      = f2bf(lo * cs - hi * sn);
  buf[base + 64] = f2bf(hi * cs + lo * sn);
}

// ---------------------------------------------------------------------------
// Transpose V: in[m=b*2048+s][n(512)] -> out[(b*512+n)*2048 + s]. 64x64 LDS
// tiles, coalesced 16B on both sides. grid (128, 8), 256 threads.
// ---------------------------------------------------------------------------
__global__ __launch_bounds__(256) void trans_kernel(const short* __restrict__ in,
                                                    short* __restrict__ out)
{
  __shared__ short T[64 * 72];
  const int t = threadIdx.x;
  const int ms = blockIdx.x * 64;   // global m (= b*2048 + s) tile base
  const int ns = blockIdx.y * 64;   // n tile base
  const int b = ms >> 11;
  const int sl = ms & 2047;
  const int r = t >> 3, sg = t & 7;
#pragma unroll
  for (int j = 0; j < 2; ++j) {
    const uint4 v = *(const uint4*)(in + (size_t)(ms + r + 32 * j) * 512 + ns + sg * 8);
    *(uint4*)&T[(r + 32 * j) * 72 + sg * 8] = v;
  }
  __syncthreads();
#pragma unroll
  for (int j = 0; j < 2; ++j) {
    const int nr = r + 32 * j;
    s16x8 v;
#pragma unroll
    for (int i = 0; i < 8; ++i) v[i] = T[(sg * 8 + i) * 72 + nr];
    *(s16x8*)(out + ((size_t)(b * 512 + ns + nr)) * 2048 + sl + sg * 8) = v;
  }
}

// ---------------------------------------------------------------------------
// Flash attention, causal, GQA (kv = h>>2). LDS-staged + latency-overlapped
// (structure from r2). r4: raw-st softmax (SC folded into exp2 via fma),
// v_cvt_pk_bf16_f32 P-packing, exact rescale-skip (alpha==1 tiles), setprio
// around MFMA clusters.
// ---------------------------------------------------------------------------
__global__ __launch_bounds__(512, 4) void attn_kernel(
    const short* __restrict__ qg, const short* __restrict__ kg,
    const short* __restrict__ vtg, short* __restrict__ og)
{
  __shared__ __align__(16) short Ksm[64 * 128];   // [key][d], swizzled
  __shared__ __align__(16) short Vsm[128 * 64];   // [d][key], swizzled
  __shared__ __align__(16) short Psm[128 * 64];   // [q][key], swizzled

  const int t = threadIdx.x;
  const int l = t & 63;
  const int w = t >> 6;
  const int lane16 = l & 15;
  const int quad = l >> 4;
  const int jb = blockIdx.x;
  const int h = blockIdx.y, b = blockIdx.z;
  const int kv = h >> 2;

  const int krow = t >> 4, kseg = t & 15;
  const int vrow = t >> 3, vseg = t & 7;
  const int kswz = (kseg ^ (krow & 7)) * 8;
  const int vswz = (vseg ^ (vrow & 7)) * 8;

  const short* kbaseptr = kg + ((size_t)(b * 2048)) * 512 + kv * 128;
  const short* vbaseptr = vtg + ((size_t)(b * 512 + kv * 128)) * 2048;

  const float SC = 0.08838834764831845f * 1.4426950408889634f; // rsqrt(128)*log2e
  const f32x4 zero = {0.f, 0.f, 0.f, 0.f};
  const int swz = (lane16 & 7) << 3;

  uint4 kr0, kr1, vr0, vr1;
#define LOADT(KB)                                                             \
  do {                                                                        \
    kr0 = *(const uint4*)(kbaseptr + (size_t)((KB) + krow) * 512 + kseg * 8); \
    kr1 = *(const uint4*)(kbaseptr + (size_t)((KB) + 32 + krow) * 512 + kseg * 8); \
    vr0 = *(const uint4*)(vbaseptr + (size_t)(vrow) * 2048 + (KB) + vseg * 8);     \
    vr1 = *(const uint4*)(vbaseptr + (size_t)(64 + vrow) * 2048 + (KB) + vseg * 8);\
  } while (0)
#define WRITET()                                                              \
  do {                                                                        \
    *(uint4*)&Ksm[krow * 128 + kswz] = kr0;                                   \
    *(uint4*)&Ksm[(32 + krow) * 128 + kswz] = kr1;                            \
    *(uint4*)&Vsm[vrow * 64 + vswz] = vr0;                                    \
    *(uint4*)&Vsm[(64 + vrow) * 64 + vswz] = vr1;                             \
  } while (0)

  for (int sp2 = 0; sp2 < 2; ++sp2) {
    const int jj = sp2 ? (15 - jb) : jb;
    const int qb0 = jj * 128;
    const int qw0 = qb0 + w * 16;
    const int qmaxw = qw0 + 15;
    const int ntl = 2 * jj + 2;

    s16x8 qf[4];
    {
      const short* qrow =
          qg + ((size_t)(b * 2048 + qw0 + lane16)) * 2048 + h * 128 + quad * 8;
#pragma unroll
      for (int kk = 0; kk < 4; ++kk) qf[kk] = *(const s16x8*)(qrow + kk * 32);
    }

    f32x4 o[8];
#pragma unroll
    for (int i = 0; i < 8; ++i) o[i] = zero;
    float m_i = NEGH, l_i = 0.f;

    LOADT(0);
    WRITET();

    for (int tl = 0; tl < ntl; ++tl) {
      __syncthreads();
      const int kbase = tl * 64;
      if (tl + 1 < ntl) LOADT((tl + 1) * 64);

      if (kbase <= qmaxw) {
        f32x4 st[4];
#pragma unroll
        for (int mt = 0; mt < 4; ++mt) st[mt] = zero;
        __builtin_amdgcn_s_setprio(1);
#pragma unroll
        for (int mt = 0; mt < 4; ++mt) {
          const int rb = (mt * 16 + lane16) * 128;
#pragma unroll
          for (int kk = 0; kk < 4; ++kk) {
            const s16x8 a = *(const s16x8*)&Ksm[rb + ((kk * 32 + quad * 8) ^ swz)];
            st[mt] = __builtin_amdgcn_mfma_f32_16x16x32_bf16(a, qf[kk], st[mt], 0, 0, 0);
          }
        }
        __builtin_amdgcn_s_setprio(0);

        // ---- softmax on raw st (SC folded into exp2 args) ----
        const bool maskt = (kbase + 63 > qw0);
        const int qabs = qw0 + lane16;
        float tl_ = NEGH;
        if (maskt) {
#pragma unroll
          for (int mt = 0; mt < 4; ++mt)
#pragma unroll
            for (int r = 0; r < 4; ++r) {
              float xx = st[mt][r];
              if ((kbase + mt * 16 + quad * 4 + r) > qabs) xx = NEGH;
              st[mt][r] = xx;
              tl_ = fmaxf(tl_, xx);
            }
        } else {
#pragma unroll
          for (int mt = 0; mt < 4; ++mt)
#pragma unroll
            for (int r = 0; r < 4; ++r) tl_ = fmaxf(tl_, st[mt][r]);
        }
        tl_ = fmaxf(tl_, __shfl_xor(tl_, 16));
        tl_ = fmaxf(tl_, __shfl_xor(tl_, 32));
        const float mnew = fmaxf(m_i, tl_);
        // exact skip: if no lane's tile-max exceeds the running max, alpha==1
        if (!__all(tl_ <= m_i)) {
          const float alpha = exp2f((m_i - mnew) * SC);
          l_i *= alpha;
#pragma unroll
          for (int r = 0; r < 4; ++r) {
            const float ar = __shfl(alpha, quad * 4 + r);
#pragma unroll
            for (int ntd = 0; ntd < 8; ++ntd) o[ntd][r] *= ar;
          }
        }
        m_i = mnew;
        const float mS = mnew * SC;
        float rs = 0.f;
#pragma unroll
        for (int mt = 0; mt < 4; ++mt) {
          const float p0 = exp2f(fmaf(st[mt][0], SC, -mS));
          const float p1 = exp2f(fmaf(st[mt][1], SC, -mS));
          const float p2 = exp2f(fmaf(st[mt][2], SC, -mS));
          const float p3 = exp2f(fmaf(st[mt][3], SC, -mS));
          rs += (p0 + p1) + (p2 + p3);
          uint2 pk2;
          asm("v_cvt_pk_bf16_f32 %0, %1, %2" : "=v"(pk2.x) : "v"(p0), "v"(p1));
          asm("v_cvt_pk_bf16_f32 %0, %1, %2" : "=v"(pk2.y) : "v"(p2), "v"(p3));
          *(uint2*)&Psm[(w * 16 + lane16) * 64 + ((mt * 16 + quad * 4) ^ swz)] = pk2;
        }
        rs += __shfl_xor(rs, 16);
        rs += __shfl_xor(rs, 32);
        l_i += rs;

        // PV: O[q][d] += P[q][key] * Vt[d][key]
        const int prb = (w * 16 + lane16) * 64;
        __builtin_amdgcn_s_setprio(1);
#pragma unroll
        for (int kk = 0; kk < 2; ++kk) {
          const s16x8 pf = *(const s16x8*)&Psm[prb + ((kk * 32 + quad * 8) ^ swz)];
#pragma unroll
          for (int ntd = 0; ntd < 8; ++ntd) {
            const s16x8 vf =
                *(const s16x8*)&Vsm[(ntd * 16 + lane16) * 64 + ((kk * 32 + quad * 8) ^ swz)];
            o[ntd] = __builtin_amdgcn_mfma_f32_16x16x32_bf16(pf, vf, o[ntd], 0, 0, 0);
          }
        }
        __builtin_amdgcn_s_setprio(0);
      }

      __syncthreads();
      if (tl + 1 < ntl) WRITET();
    }

#pragma unroll
    for (int r = 0; r < 4; ++r) {
      const float lr = __shfl(l_i, quad * 4 + r);
      const float inv = 1.f / lr;
      const size_t base =
          ((size_t)(b * 2048 + qw0 + quad * 4 + r)) * 2048 + h * 128 + lane16;
#pragma unroll
      for (int ntd = 0; ntd < 8; ++ntd) og[base + ntd * 16] = f2bf(o[ntd][r] * inv);
    }
  }
#undef LOADT
#undef WRITET
}

// ---------------------------------------------------------------------------
extern "C" void kernel_launch(void* const* d_in, const int* in_sizes, int n_in,
                              void* d_out, int out_size, void* d_ws,
                              size_t ws_size, hipStream_t stream)
{
  const float* x  = (const float*)d_in[0];
  const float* wq = (const float*)d_in[1];
  const float* bq = (const float*)d_in[2];
  const float* wk = (const float*)d_in[3];
  const float* bk = (const float*)d_in[4];
  const float* wv = (const float*)d_in[5];
  const float* bv = (const float*)d_in[6];
  const float* wo = (const float*)d_in[7];
  const float* bo = (const float*)d_in[8];
  float* out = (float*)d_out;

  // ws layout (77 MiB used; ws_size >= 80 MiB):
  //   xb  @0      32 MiB  [8192][2048] bf16; dead after KV-proj -> wob reuses @0
  //   wqb @32MiB   8 MiB; wkb @40MiB 2 MiB; wvb @42MiB 2 MiB (wkb||wvb = [1024][2048])
  //   qws @44MiB  32 MiB  [8192][2048] bf16; attention output in place
  //   tab @76MiB   1 MiB  float2[2048][64] rope cos/sin
  // d_out doubles as scratch: kws @out+0 8 MiB; vtw @out+8M 8 MiB; vtmp @out+16M 8 MiB
  char* ws = (char*)d_ws;
  short* xb  = (short*)ws;
  short* wqb = (short*)(ws + (32ull << 20));
  short* wkb = (short*)(ws + (40ull << 20));
  short* wvb = (short*)(ws + (42ull << 20));
  short* qws = (short*)(ws + (44ull << 20));
  float2* tab = (float2*)(ws + (76ull << 20));
  short* wob = xb;
  short* kws = (short*)d_out;
  short* vtw = (short*)((char*)d_out + (8ull << 20));
  short* vtmp = (short*)((char*)d_out + (16ull << 20));

  const dim3 blk(256);
  cvt_kernel<<<16384, blk, 0, stream>>>(x,  xb);
  cvt_kernel<<<4096,  blk, 0, stream>>>(wq, wqb);
  cvt_kernel<<<1024,  blk, 0, stream>>>(wk, wkb);
  cvt_kernel<<<1024,  blk, 0, stream>>>(wv, wvb);
  rope_tab_kernel<<<512, blk, 0, stream>>>(tab);
  // projections: Q on 256^2 8-phase; K+V merged (wkb||wvb contiguous), V row-major
  gemm256_bt<<<dim3(8, 32), dim3(512), 0, stream>>>(xb, wqb, bq, qws, 8192, 2048, 2048, 0);
  gemm_bt<<<dim3(8, 64), blk, 0, stream>>>(xb, wkb, bk, bv, kws, vtmp, 8192, 1024, 2048, 3);
  trans_kernel<<<dim3(128, 8), blk, 0, stream>>>(vtmp, vtw);
  rope_kernel<<<32768, blk, 0, stream>>>(qws, 4, tab);
  rope_kernel<<<8192,  blk, 0, stream>>>(kws, 2, tab);
  cvt_kernel<<<4096, blk, 0, stream>>>(wo, wob);
  attn_kernel<<<dim3(8, 16, 4), dim3(512), 0, stream>>>(qws, kws, vtw, qws);
  gemm256_bt<<<dim3(8, 32), dim3(512), 0, stream>>>(qws, wob, bo, out, 8192, 2048, 2048, 1);
}

// Round 5
// 531.093 us; speedup vs baseline: 1.7780x; 1.0032x over previous
//
#include <hip/hip_runtime.h>
#include <stdint.h>
#include <math.h>

typedef __attribute__((ext_vector_type(8))) short s16x8;
typedef __attribute__((ext_vector_type(4))) short s16x4;
typedef __attribute__((ext_vector_type(4))) float f32x4;

#define NEGH (-1.0e30f)

__device__ __forceinline__ short f2bf(float f) {
  union { float f; unsigned int i; } c; c.f = f;
  unsigned int lsb = (c.i >> 16) & 1u;
  c.i += 0x7fffu + lsb;
  return (short)(c.i >> 16);
}
__device__ __forceinline__ float bf2f(short u) {
  union { unsigned int i; float f; } c;
  c.i = ((unsigned int)(unsigned short)u) << 16;
  return c.f;
}

// async global->LDS, 16B per lane. LDS dest must be wave-uniform base + lane*16.
#define GLOAD_LDS16(gp, lp)                                                  \
  __builtin_amdgcn_global_load_lds(                                          \
      (__attribute__((address_space(1))) void*)(void*)(gp),                  \
      (__attribute__((address_space(3))) void*)(lp), 16, 0, 0)

// ---------------------------------------------------------------------------
// fp32 -> bf16 conversion, 4 elements/thread. n must be divisible by 1024.
// ---------------------------------------------------------------------------
__global__ __launch_bounds__(256) void cvt_kernel(const float* __restrict__ in,
                                                  short* __restrict__ out)
{
  const size_t i = ((size_t)blockIdx.x * 256 + threadIdx.x) * 4;
  const float4 v = *(const float4*)(in + i);
  s16x4 o = { f2bf(v.x), f2bf(v.y), f2bf(v.z), f2bf(v.w) };
  *(s16x4*)(out + i) = o;
}

// ---------------------------------------------------------------------------
// GEMM (small-N): C[M,N] = A[M,K] * W[N,K]^T + bias[N]. 128x128 tile, BK=64,
// 256 threads. omode: 0 = bf16 C row-major; 1 = fp32 C row-major;
// 3 = split KV: n<512 -> bf16 C[m*512+n] (bias), n>=512 -> bf16 C2[m*512+n-512]
//     (bias2). 512-boundary is block-uniform (nb0 multiple of 128).
// XCD swizzle (only for grid 8x64): each XCD owns 8 y-panels x 8 x-blocks so
// the A-panel + full B fit its private L2 (A re-fetch was ~8x without it).
// ---------------------------------------------------------------------------
__global__ __launch_bounds__(256) void gemm_bt(
    const short* __restrict__ A, const short* __restrict__ W,
    const float* __restrict__ bias, const float* __restrict__ bias2,
    void* __restrict__ C, void* __restrict__ C2,
    int M, int N, int K, int omode)
{
  __shared__ __align__(16) short As[128 * 64];
  __shared__ __align__(16) short Bs[128 * 64];

  const int t = threadIdx.x;
  const int l = t & 63;
  const int w = t >> 6;
  const int lane16 = l & 15;
  const int quad = l >> 4;
  const int wm = w >> 1, wn = w & 1;

  int bx = blockIdx.x, by = blockIdx.y;
  if (gridDim.x == 8 && gridDim.y == 64) {       // KV call: XCD-aware remap
    const int lid = blockIdx.x + 8 * blockIdx.y; // 0..511, x fastest
    const int xcd = lid & 7, idx = lid >> 3;     // idx 0..63
    by = xcd * 8 + (idx >> 3);                   // 0..63
    bx = idx & 7;                                // 0..7
  }
  const int mb0 = by * 128;
  const int nb0 = bx * 128;

  const f32x4 zero = {0.f, 0.f, 0.f, 0.f};
  f32x4 acc[4][4];
#pragma unroll
  for (int i = 0; i < 4; ++i)
#pragma unroll
    for (int j = 0; j < 4; ++j) acc[i][j] = zero;

  const int sr = t >> 3;
  const int sp = t & 7;
  const short* Ag = A + (size_t)(mb0 + sr) * K + sp * 8;
  const short* Wg = W + (size_t)(nb0 + sr) * K + sp * 8;
  short* Al = As + t * 8;
  short* Bl = Bs + t * 8;

  const int nkt = K >> 6;
  for (int kt = 0; kt < nkt; ++kt) {
    __syncthreads();
    const int kof = kt * 64;
#pragma unroll
    for (int it = 0; it < 4; ++it) {
      GLOAD_LDS16(Ag + kof + (size_t)(it * 32) * K, Al + it * 2048);
      GLOAD_LDS16(Wg + kof + (size_t)(it * 32) * K, Bl + it * 2048);
    }
    __syncthreads();
#pragma unroll
    for (int kk = 0; kk < 2; ++kk) {
      s16x8 af[4], bf[4];
#pragma unroll
      for (int mi = 0; mi < 4; ++mi)
        af[mi] = *(const s16x8*)&As[(wm * 64 + mi * 16 + lane16) * 64 +
                                    kk * 32 + quad * 8];
#pragma unroll
      for (int ni = 0; ni < 4; ++ni)
        bf[ni] = *(const s16x8*)&Bs[(wn * 64 + ni * 16 + lane16) * 64 +
                                    kk * 32 + quad * 8];
#pragma unroll
      for (int mi = 0; mi < 4; ++mi)
#pragma unroll
        for (int ni = 0; ni < 4; ++ni)
          acc[mi][ni] = __builtin_amdgcn_mfma_f32_16x16x32_bf16(
              af[mi], bf[ni], acc[mi][ni], 0, 0, 0);
    }
  }

#pragma unroll
  for (int ni = 0; ni < 4; ++ni) {
    const int n = nb0 + wn * 64 + ni * 16 + lane16;
    const float bvx = (omode == 3 && n >= 512) ? bias2[n - 512] : bias[n];
#pragma unroll
    for (int mi = 0; mi < 4; ++mi) {
      const int m0 = mb0 + wm * 64 + mi * 16 + quad * 4;
#pragma unroll
      for (int r = 0; r < 4; ++r) {
        const int m = m0 + r;
        const float v = acc[mi][ni][r] + bvx;
        if (omode == 0) {
          ((short*)C)[(size_t)m * N + n] = f2bf(v);
        } else if (omode == 1) {
          ((float*)C)[(size_t)m * N + n] = v;
        } else {
          if (n < 512) ((short*)C)[(size_t)m * 512 + n] = f2bf(v);
          else         ((short*)C2)[(size_t)m * 512 + (n - 512)] = f2bf(v);
        }
      }
    }
  }
}

// ---------------------------------------------------------------------------
// GEMM (big): 256x256 tile, BK=64, 512 threads = 8 waves (2M x 4N), 8-phase
// schedule (T2+T3+T4+T5). See r3 comments; vmcnt(10) audit: each even-phase
// wait retires exactly the half-tiles the next two phases read (zero slack).
// r5: XCD-aware block remap (grid 8x32 = 256 blocks): each XCD owns a 2x16
// chunk (2 N-tiles x 16 M-tiles) -> B working set 2MB + A panel 1MB < 4MB L2.
// omode: 0 = bf16 C; 1 = fp32 C.
// ---------------------------------------------------------------------------
__global__ __launch_bounds__(512, 2) void gemm256_bt(
    const short* __restrict__ A, const short* __restrict__ W,
    const float* __restrict__ bias, void* __restrict__ C,
    int M, int N, int K, int omode)
{
  __shared__ __align__(16) short Asm[2 * 16384];   // [buf][kk][row][32]
  __shared__ __align__(16) short Bsm[2 * 16384];

  const int t = threadIdx.x;
  const int l = t & 63;
  const int w = t >> 6;                // 0..7
  const int lane16 = l & 15;
  const int quad = l >> 4;
  const int wm = w >> 2;               // 0..1
  const int wn = w & 3;                // 0..3

  int bx = blockIdx.x, by = blockIdx.y;
  if (gridDim.x == 8 && gridDim.y == 32) {
    const int bid = blockIdx.y * 8 + blockIdx.x;   // 0..255, x fastest
    const int xcd = bid & 7, idx = bid >> 3;       // idx 0..31
    const int xc = xcd & 3, yc = xcd >> 2;         // 4 x-chunks x 2 y-chunks
    bx = xc * 2 + (idx & 1);                       // 0..7
    by = yc * 16 + (idx >> 1);                     // 0..31
  }
  const int mb0 = by * 256;
  const int nb0 = bx * 256;

  const f32x4 zero = {0.f, 0.f, 0.f, 0.f};
  f32x4 acc[8][4];
#pragma unroll
  for (int i = 0; i < 8; ++i)
#pragma unroll
    for (int j = 0; j < 4; ++j) acc[i][j] = zero;

  const int srow = t >> 2;                       // 0..127
  const int scs = (t & 3) ^ ((t >> 3) & 3);      // pre-swizzled source chunk
  const short* Ag = A + (size_t)(mb0 + srow) * K + scs * 8;
  const short* Wg = W + (size_t)(nb0 + srow) * K + scs * 8;
  const size_t rstep = (size_t)128 * K;

#define STAGE_A(b, kt, kh)                                                    \
  do {                                                                        \
    const size_t ko_ = (size_t)(kt) * 64 + (kh) * 32;                         \
    GLOAD_LDS16(Ag + ko_,         Asm + (b) * 16384 + (kh) * 8192 + t * 8);   \
    GLOAD_LDS16(Ag + ko_ + rstep, Asm + (b) * 16384 + (kh) * 8192 + 4096 + t * 8); \
  } while (0)
#define STAGE_B(b, kt, kh)                                                    \
  do {                                                                        \
    const size_t ko_ = (size_t)(kt) * 64 + (kh) * 32;                         \
    GLOAD_LDS16(Wg + ko_,         Bsm + (b) * 16384 + (kh) * 8192 + t * 8);   \
    GLOAD_LDS16(Wg + ko_ + rstep, Bsm + (b) * 16384 + (kh) * 8192 + 4096 + t * 8); \
  } while (0)

  s16x8 bfr[4];

#define DO_PHASE(BUF, KK, MG, READB, STAGE_STMT, DO_VM)                       \
  {                                                                           \
    const short* Abase = Asm + (BUF) * 16384 + (KK) * 8192;                   \
    const short* Bbase = Bsm + (BUF) * 16384 + (KK) * 8192;                   \
    if (READB) {                                                              \
      _Pragma("unroll")                                                       \
      for (int ni = 0; ni < 4; ++ni) {                                        \
        const int nr = wn * 64 + ni * 16 + lane16;                            \
        bfr[ni] = *(const s16x8*)(Bbase + nr * 32 +                           \
                                  ((quad ^ ((nr >> 1) & 3)) << 3));           \
      }                                                                       \
    }                                                                         \
    s16x8 afr[4];                                                             \
    _Pragma("unroll")                                                         \
    for (int mi2 = 0; mi2 < 4; ++mi2) {                                       \
      const int mr = wm * 128 + (MG) * 64 + mi2 * 16 + lane16;                \
      afr[mi2] = *(const s16x8*)(Abase + mr * 32 +                            \
                                 ((quad ^ ((mr >> 1) & 3)) << 3));            \
    }                                                                         \
    STAGE_STMT;                                                               \
    __builtin_amdgcn_s_barrier();                                             \
    asm volatile("s_waitcnt lgkmcnt(0)" ::: "memory");                        \
    __builtin_amdgcn_sched_barrier(0);                                        \
    __builtin_amdgcn_s_setprio(1);                                            \
    _Pragma("unroll")                                                         \
    for (int mi2 = 0; mi2 < 4; ++mi2)                                         \
      _Pragma("unroll")                                                       \
      for (int ni = 0; ni < 4; ++ni)                                          \
        acc[(MG) * 4 + mi2][ni] = __builtin_amdgcn_mfma_f32_16x16x32_bf16(    \
            afr[mi2], bfr[ni], acc[(MG) * 4 + mi2][ni], 0, 0, 0);             \
    __builtin_amdgcn_s_setprio(0);                                            \
    if (DO_VM) {                                                              \
      asm volatile("s_waitcnt vmcnt(10)" ::: "memory");                       \
      __builtin_amdgcn_sched_barrier(0);                                      \
    }                                                                         \
    __builtin_amdgcn_s_barrier();                                             \
  }

  const int NT = K >> 6;               // K-tiles (even; >= 2)

  STAGE_B(0, 0, 0); STAGE_A(0, 0, 0); STAGE_B(0, 0, 1); STAGE_A(0, 0, 1);
  STAGE_B(1, 1, 0); STAGE_A(1, 1, 0); STAGE_B(1, 1, 1);
  asm volatile("s_waitcnt vmcnt(10)" ::: "memory");
  __builtin_amdgcn_sched_barrier(0);
  __builtin_amdgcn_s_barrier();

  for (int i2 = 0; i2 < NT; i2 += 2) {
    const int tp1 = (i2 + 1 < NT) ? i2 + 1 : NT - 1;
    const int tp2 = (i2 + 2 < NT) ? i2 + 2 : NT - 1;
    const int tp3 = (i2 + 3 < NT) ? i2 + 3 : NT - 1;
    DO_PHASE(0, 0, 0, true,  STAGE_A(1, tp1, 1), false)   // P1
    DO_PHASE(0, 0, 1, false, STAGE_B(0, tp2, 0), true)    // P2
    DO_PHASE(0, 1, 0, true,  STAGE_A(0, tp2, 0), false)   // P3
    DO_PHASE(0, 1, 1, false, STAGE_B(0, tp2, 1), true)    // P4
    DO_PHASE(1, 0, 0, true,  STAGE_A(0, tp2, 1), false)   // P5
    DO_PHASE(1, 0, 1, false, STAGE_B(1, tp3, 0), true)    // P6
    DO_PHASE(1, 1, 0, true,  STAGE_A(1, tp3, 0), false)   // P7
    DO_PHASE(1, 1, 1, false, STAGE_B(1, tp3, 1), true)    // P8
  }

#pragma unroll
  for (int ni = 0; ni < 4; ++ni) {
    const int n = nb0 + wn * 64 + ni * 16 + lane16;
    const float bv = bias[n];
#pragma unroll
    for (int mi = 0; mi < 8; ++mi) {
      const int m0 = mb0 + wm * 128 + mi * 16 + quad * 4;
#pragma unroll
      for (int r = 0; r < 4; ++r) {
        const float v = acc[mi][ni][r] + bv;
        if (omode == 0) ((short*)C)[(size_t)(m0 + r) * N + n] = f2bf(v);
        else            ((float*)C)[(size_t)(m0 + r) * N + n] = v;
      }
    }
  }
#undef DO_PHASE
#undef STAGE_A
#undef STAGE_B
}

// ---------------------------------------------------------------------------
// RoPE cos/sin table: tab[pos*64 + d] = {cos, sin}(pos * invfreq(d)).
// ---------------------------------------------------------------------------
__global__ __launch_bounds__(256) void rope_tab_kernel(float2* __restrict__ tab)
{
  const int i = blockIdx.x * 256 + threadIdx.x;    // 131072
  const int pos = i >> 6, d = i & 63;
  const float fr = (float)pos * exp2f((float)d * -0.20762050593048584f);
  float sn, cs;
  sincosf(fr, &sn, &cs);
  tab[i] = make_float2(cs, sn);
}

// ---------------------------------------------------------------------------
// RoPE in place on bf16 buf[row][head*128 + d], pairs (d, d+64), pos = row%2048.
// ---------------------------------------------------------------------------
__global__ __launch_bounds__(256) void rope_kernel(short* __restrict__ buf,
                                                   int lognh,
                                                   const float2* __restrict__ tab)
{
  const int idx = blockIdx.x * 256 + threadIdx.x;
  const int d = idx & 63;
  const int rest = idx >> 6;            // row*nh + h
  const int row = rest >> lognh;
  const int pos = row & 2047;
  const float2 cssn = tab[(pos << 6) | d];
  const float cs = cssn.x, sn = cssn.y;
  const size_t base = (size_t)rest * 128 + d;
  const float lo = bf2f(buf[base]);
  const float hi = bf2f(buf[base + 64]);
  buf[base]      = f2bf(lo * cs - hi * sn);
  buf[base + 64] = f2bf(hi * cs + lo * sn);
}

// ---------------------------------------------------------------------------
// Transpose V: in[m=b*2048+s][n(512)] -> out[(b*512+n)*2048 + s]. 64x64 LDS
// tiles, coalesced 16B on both sides. grid (128, 8), 256 threads.
// ---------------------------------------------------------------------------
__global__ __launch_bounds__(256) void trans_kernel(const short* __restrict__ in,
                                                    short* __restrict__ out)
{
  __shared__ short T[64 * 72];
  const int t = threadIdx.x;
  const int ms = blockIdx.x * 64;   // global m (= b*2048 + s) tile base
  const int ns = blockIdx.y * 64;   // n tile base
  const int b = ms >> 11;
  const int sl = ms & 2047;
  const int r = t >> 3, sg = t & 7;
#pragma unroll
  for (int j = 0; j < 2; ++j) {
    const uint4 v = *(const uint4*)(in + (size_t)(ms + r + 32 * j) * 512 + ns + sg * 8);
    *(uint4*)&T[(r + 32 * j) * 72 + sg * 8] = v;
  }
  __syncthreads();
#pragma unroll
  for (int j = 0; j < 2; ++j) {
    const int nr = r + 32 * j;
    s16x8 v;
#pragma unroll
    for (int i = 0; i < 8; ++i) v[i] = T[(sg * 8 + i) * 72 + nr];
    *(s16x8*)(out + ((size_t)(b * 512 + ns + nr)) * 2048 + sl + sg * 8) = v;
  }
}

// ---------------------------------------------------------------------------
// Flash attention, causal, GQA. LDS-staged + latency-overlapped (r2 structure,
// r4 softmax). r5: XCD-aware block remap -- each XCD owns exactly two whole
// (b,kv) groups, so each K/V panel (1 MiB) is fetched by ONE XCD's L2 only.
// ---------------------------------------------------------------------------
__global__ __launch_bounds__(512, 4) void attn_kernel(
    const short* __restrict__ qg, const short* __restrict__ kg,
    const short* __restrict__ vtg, short* __restrict__ og)
{
  __shared__ __align__(16) short Ksm[64 * 128];   // [key][d], swizzled
  __shared__ __align__(16) short Vsm[128 * 64];   // [d][key], swizzled
  __shared__ __align__(16) short Psm[128 * 64];   // [q][key], swizzled

  const int t = threadIdx.x;
  const int l = t & 63;
  const int w = t >> 6;
  const int lane16 = l & 15;
  const int quad = l >> 4;

  // XCD remap: lid 0..511 -> (xcd, idx); group g = (b,kv) in 0..15; two groups
  // per XCD; within group: h = kv*4 + (wv>>3), jb = wv&7.
  const int lid = blockIdx.x + 8 * (blockIdx.y + 16 * blockIdx.z);
  const int xcd = lid & 7, idx = lid >> 3;        // idx 0..63
  const int g = xcd * 2 + (idx >> 5);             // 0..15
  const int wv_ = idx & 31;
  const int b = g >> 2, kv = g & 3;
  const int h = kv * 4 + (wv_ >> 3);
  const int jb = wv_ & 7;

  const int krow = t >> 4, kseg = t & 15;
  const int vrow = t >> 3, vseg = t & 7;
  const int kswz = (kseg ^ (krow & 7)) * 8;
  const int vswz = (vseg ^ (vrow & 7)) * 8;

  const short* kbaseptr = kg + ((size_t)(b * 2048)) * 512 + kv * 128;
  const short* vbaseptr = vtg + ((size_t)(b * 512 + kv * 128)) * 2048;

  const float SC = 0.08838834764831845f * 1.4426950408889634f; // rsqrt(128)*log2e
  const f32x4 zero = {0.f, 0.f, 0.f, 0.f};
  const int swz = (lane16 & 7) << 3;

  uint4 kr0, kr1, vr0, vr1;
#define LOADT(KB)                                                             \
  do {                                                                        \
    kr0 = *(const uint4*)(kbaseptr + (size_t)((KB) + krow) * 512 + kseg * 8); \
    kr1 = *(const uint4*)(kbaseptr + (size_t)((KB) + 32 + krow) * 512 + kseg * 8); \
    vr0 = *(const uint4*)(vbaseptr + (size_t)(vrow) * 2048 + (KB) + vseg * 8);     \
    vr1 = *(const uint4*)(vbaseptr + (size_t)(64 + vrow) * 2048 + (KB) + vseg * 8);\
  } while (0)
#define WRITET()                                                              \
  do {                                                                        \
    *(uint4*)&Ksm[krow * 128 + kswz] = kr0;                                   \
    *(uint4*)&Ksm[(32 + krow) * 128 + kswz] = kr1;                            \
    *(uint4*)&Vsm[vrow * 64 + vswz] = vr0;                                    \
    *(uint4*)&Vsm[(64 + vrow) * 64 + vswz] = vr1;                             \
  } while (0)

  for (int sp2 = 0; sp2 < 2; ++sp2) {
    const int jj = sp2 ? (15 - jb) : jb;
    const int qb0 = jj * 128;
    const int qw0 = qb0 + w * 16;
    const int qmaxw = qw0 + 15;
    const int ntl = 2 * jj + 2;

    s16x8 qf[4];
    {
      const short* qrow =
          qg + ((size_t)(b * 2048 + qw0 + lane16)) * 2048 + h * 128 + quad * 8;
#pragma unroll
      for (int kk = 0; kk < 4; ++kk) qf[kk] = *(const s16x8*)(qrow + kk * 32);
    }

    f32x4 o[8];
#pragma unroll
    for (int i = 0; i < 8; ++i) o[i] = zero;
    float m_i = NEGH, l_i = 0.f;

    LOADT(0);
    WRITET();

    for (int tl = 0; tl < ntl; ++tl) {
      __syncthreads();
      const int kbase = tl * 64;
      if (tl + 1 < ntl) LOADT((tl + 1) * 64);

      if (kbase <= qmaxw) {
        f32x4 st[4];
#pragma unroll
        for (int mt = 0; mt < 4; ++mt) st[mt] = zero;
        __builtin_amdgcn_s_setprio(1);
#pragma unroll
        for (int mt = 0; mt < 4; ++mt) {
          const int rb = (mt * 16 + lane16) * 128;
#pragma unroll
          for (int kk = 0; kk < 4; ++kk) {
            const s16x8 a = *(const s16x8*)&Ksm[rb + ((kk * 32 + quad * 8) ^ swz)];
            st[mt] = __builtin_amdgcn_mfma_f32_16x16x32_bf16(a, qf[kk], st[mt], 0, 0, 0);
          }
        }
        __builtin_amdgcn_s_setprio(0);

        // ---- softmax on raw st (SC folded into exp2 args) ----
        const bool maskt = (kbase + 63 > qw0);
        const int qabs = qw0 + lane16;
        float tl_ = NEGH;
        if (maskt) {
#pragma unroll
          for (int mt = 0; mt < 4; ++mt)
#pragma unroll
            for (int r = 0; r < 4; ++r) {
              float xx = st[mt][r];
              if ((kbase + mt * 16 + quad * 4 + r) > qabs) xx = NEGH;
              st[mt][r] = xx;
              tl_ = fmaxf(tl_, xx);
            }
        } else {
#pragma unroll
          for (int mt = 0; mt < 4; ++mt)
#pragma unroll
            for (int r = 0; r < 4; ++r) tl_ = fmaxf(tl_, st[mt][r]);
        }
        tl_ = fmaxf(tl_, __shfl_xor(tl_, 16));
        tl_ = fmaxf(tl_, __shfl_xor(tl_, 32));
        const float mnew = fmaxf(m_i, tl_);
        // exact skip: if no lane's tile-max exceeds the running max, alpha==1
        if (!__all(tl_ <= m_i)) {
          const float alpha = exp2f((m_i - mnew) * SC);
          l_i *= alpha;
#pragma unroll
          for (int r = 0; r < 4; ++r) {
            const float ar = __shfl(alpha, quad * 4 + r);
#pragma unroll
            for (int ntd = 0; ntd < 8; ++ntd) o[ntd][r] *= ar;
          }
        }
        m_i = mnew;
        const float mS = mnew * SC;
        float rs = 0.f;
#pragma unroll
        for (int mt = 0; mt < 4; ++mt) {
          const float p0 = exp2f(fmaf(st[mt][0], SC, -mS));
          const float p1 = exp2f(fmaf(st[mt][1], SC, -mS));
          const float p2 = exp2f(fmaf(st[mt][2], SC, -mS));
          const float p3 = exp2f(fmaf(st[mt][3], SC, -mS));
          rs += (p0 + p1) + (p2 + p3);
          uint2 pk2;
          asm("v_cvt_pk_bf16_f32 %0, %1, %2" : "=v"(pk2.x) : "v"(p0), "v"(p1));
          asm("v_cvt_pk_bf16_f32 %0, %1, %2" : "=v"(pk2.y) : "v"(p2), "v"(p3));
          *(uint2*)&Psm[(w * 16 + lane16) * 64 + ((mt * 16 + quad * 4) ^ swz)] = pk2;
        }
        rs += __shfl_xor(rs, 16);
        rs += __shfl_xor(rs, 32);
        l_i += rs;

        // PV: O[q][d] += P[q][key] * Vt[d][key]
        const int prb = (w * 16 + lane16) * 64;
        __builtin_amdgcn_s_setprio(1);
#pragma unroll
        for (int kk = 0; kk < 2; ++kk) {
          const s16x8 pf = *(const s16x8*)&Psm[prb + ((kk * 32 + quad * 8) ^ swz)];
#pragma unroll
          for (int ntd = 0; ntd < 8; ++ntd) {
            const s16x8 vf =
                *(const s16x8*)&Vsm[(ntd * 16 + lane16) * 64 + ((kk * 32 + quad * 8) ^ swz)];
            o[ntd] = __builtin_amdgcn_mfma_f32_16x16x32_bf16(pf, vf, o[ntd], 0, 0, 0);
          }
        }
        __builtin_amdgcn_s_setprio(0);
      }

      __syncthreads();
      if (tl + 1 < ntl) WRITET();
    }

#pragma unroll
    for (int r = 0; r < 4; ++r) {
      const float lr = __shfl(l_i, quad * 4 + r);
      const float inv = 1.f / lr;
      const size_t base =
          ((size_t)(b * 2048 + qw0 + quad * 4 + r)) * 2048 + h * 128 + lane16;
#pragma unroll
      for (int ntd = 0; ntd < 8; ++ntd) og[base + ntd * 16] = f2bf(o[ntd][r] * inv);
    }
  }
#undef LOADT
#undef WRITET
}

// ---------------------------------------------------------------------------
extern "C" void kernel_launch(void* const* d_in, const int* in_sizes, int n_in,
                              void* d_out, int out_size, void* d_ws,
                              size_t ws_size, hipStream_t stream)
{
  const float* x  = (const float*)d_in[0];
  const float* wq = (const float*)d_in[1];
  const float* bq = (const float*)d_in[2];
  const float* wk = (const float*)d_in[3];
  const float* bk = (const float*)d_in[4];
  const float* wv = (const float*)d_in[5];
  const float* bv = (const float*)d_in[6];
  const float* wo = (const float*)d_in[7];
  const float* bo = (const float*)d_in[8];
  float* out = (float*)d_out;

  // ws layout (77 MiB used; ws_size >= 80 MiB):
  //   xb  @0      32 MiB  [8192][2048] bf16; dead after KV-proj -> wob reuses @0
  //   wqb @32MiB   8 MiB; wkb @40MiB 2 MiB; wvb @42MiB 2 MiB (wkb||wvb = [1024][2048])
  //   qws @44MiB  32 MiB  [8192][2048] bf16; attention output in place
  //   tab @76MiB   1 MiB  float2[2048][64] rope cos/sin
  // d_out doubles as scratch: kws @out+0 8 MiB; vtw @out+8M 8 MiB; vtmp @out+16M 8 MiB
  char* ws = (char*)d_ws;
  short* xb  = (short*)ws;
  short* wqb = (short*)(ws + (32ull << 20));
  short* wkb = (short*)(ws + (40ull << 20));
  short* wvb = (short*)(ws + (42ull << 20));
  short* qws = (short*)(ws + (44ull << 20));
  float2* tab = (float2*)(ws + (76ull << 20));
  short* wob = xb;
  short* kws = (short*)d_out;
  short* vtw = (short*)((char*)d_out + (8ull << 20));
  short* vtmp = (short*)((char*)d_out + (16ull << 20));

  const dim3 blk(256);
  cvt_kernel<<<16384, blk, 0, stream>>>(x,  xb);
  cvt_kernel<<<4096,  blk, 0, stream>>>(wq, wqb);
  cvt_kernel<<<1024,  blk, 0, stream>>>(wk, wkb);
  cvt_kernel<<<1024,  blk, 0, stream>>>(wv, wvb);
  rope_tab_kernel<<<512, blk, 0, stream>>>(tab);
  // projections: Q on 256^2 8-phase; K+V merged (wkb||wvb contiguous), V row-major
  gemm256_bt<<<dim3(8, 32), dim3(512), 0, stream>>>(xb, wqb, bq, qws, 8192, 2048, 2048, 0);
  gemm_bt<<<dim3(8, 64), blk, 0, stream>>>(xb, wkb, bk, bv, kws, vtmp, 8192, 1024, 2048, 3);
  trans_kernel<<<dim3(128, 8), blk, 0, stream>>>(vtmp, vtw);
  rope_kernel<<<32768, blk, 0, stream>>>(qws, 4, tab);
  rope_kernel<<<8192,  blk, 0, stream>>>(kws, 2, tab);
  cvt_kernel<<<4096, blk, 0, stream>>>(wo, wob);
  attn_kernel<<<dim3(8, 16, 4), dim3(512), 0, stream>>>(qws, kws, vtw, qws);
  gemm256_bt<<<dim3(8, 32), dim3(512), 0, stream>>>(qws, wob, bo, out, 8192, 2048, 2048, 1);
}

// Round 6
// 504.913 us; speedup vs baseline: 1.8702x; 1.0519x over previous
//
#include <hip/hip_runtime.h>
#include <stdint.h>
#include <math.h>

typedef __attribute__((ext_vector_type(8))) short s16x8;
typedef __attribute__((ext_vector_type(4))) short s16x4;
typedef __attribute__((ext_vector_type(4))) float f32x4;

#define NEGH (-1.0e30f)

__device__ __forceinline__ short f2bf(float f) {
  union { float f; unsigned int i; } c; c.f = f;
  unsigned int lsb = (c.i >> 16) & 1u;
  c.i += 0x7fffu + lsb;
  return (short)(c.i >> 16);
}
__device__ __forceinline__ float bf2f(short u) {
  union { unsigned int i; float f; } c;
  c.i = ((unsigned int)(unsigned short)u) << 16;
  return c.f;
}

// async global->LDS, 16B per lane. LDS dest must be wave-uniform base + lane*16.
#define GLOAD_LDS16(gp, lp)                                                  \
  __builtin_amdgcn_global_load_lds(                                          \
      (__attribute__((address_space(1))) void*)(void*)(gp),                  \
      (__attribute__((address_space(3))) void*)(lp), 16, 0, 0)

// ---------------------------------------------------------------------------
// fp32 -> bf16 conversion, 4 elements/thread. n must be divisible by 1024.
// ---------------------------------------------------------------------------
__global__ __launch_bounds__(256) void cvt_kernel(const float* __restrict__ in,
                                                  short* __restrict__ out)
{
  const size_t i = ((size_t)blockIdx.x * 256 + threadIdx.x) * 4;
  const float4 v = *(const float4*)(in + i);
  s16x4 o = { f2bf(v.x), f2bf(v.y), f2bf(v.z), f2bf(v.w) };
  *(s16x4*)(out + i) = o;
}

// ---------------------------------------------------------------------------
// GEMM (small-N): C[M,N] = A[M,K] * W[N,K]^T + bias[N]. 128x128 tile, BK=64,
// 256 threads. omode: 0 = bf16 C row-major; 1 = fp32 C row-major;
// 3 = split KV: n<512 -> bf16 C[m*512+n] (bias), n>=512 -> bf16 C2[m*512+n-512]
//     (bias2). XCD remap for grid 8x64 (KV call).
// ---------------------------------------------------------------------------
__global__ __launch_bounds__(256) void gemm_bt(
    const short* __restrict__ A, const short* __restrict__ W,
    const float* __restrict__ bias, const float* __restrict__ bias2,
    void* __restrict__ C, void* __restrict__ C2,
    int M, int N, int K, int omode)
{
  __shared__ __align__(16) short As[128 * 64];
  __shared__ __align__(16) short Bs[128 * 64];

  const int t = threadIdx.x;
  const int l = t & 63;
  const int w = t >> 6;
  const int lane16 = l & 15;
  const int quad = l >> 4;
  const int wm = w >> 1, wn = w & 1;

  int bx = blockIdx.x, by = blockIdx.y;
  if (gridDim.x == 8 && gridDim.y == 64) {       // KV call: XCD-aware remap
    const int lid = blockIdx.x + 8 * blockIdx.y; // 0..511, x fastest
    const int xcd = lid & 7, idx = lid >> 3;     // idx 0..63
    by = xcd * 8 + (idx >> 3);                   // 0..63
    bx = idx & 7;                                // 0..7
  }
  const int mb0 = by * 128;
  const int nb0 = bx * 128;

  const f32x4 zero = {0.f, 0.f, 0.f, 0.f};
  f32x4 acc[4][4];
#pragma unroll
  for (int i = 0; i < 4; ++i)
#pragma unroll
    for (int j = 0; j < 4; ++j) acc[i][j] = zero;

  const int sr = t >> 3;
  const int sp = t & 7;
  const short* Ag = A + (size_t)(mb0 + sr) * K + sp * 8;
  const short* Wg = W + (size_t)(nb0 + sr) * K + sp * 8;
  short* Al = As + t * 8;
  short* Bl = Bs + t * 8;

  const int nkt = K >> 6;
  for (int kt = 0; kt < nkt; ++kt) {
    __syncthreads();
    const int kof = kt * 64;
#pragma unroll
    for (int it = 0; it < 4; ++it) {
      GLOAD_LDS16(Ag + kof + (size_t)(it * 32) * K, Al + it * 2048);
      GLOAD_LDS16(Wg + kof + (size_t)(it * 32) * K, Bl + it * 2048);
    }
    __syncthreads();
#pragma unroll
    for (int kk = 0; kk < 2; ++kk) {
      s16x8 af[4], bf[4];
#pragma unroll
      for (int mi = 0; mi < 4; ++mi)
        af[mi] = *(const s16x8*)&As[(wm * 64 + mi * 16 + lane16) * 64 +
                                    kk * 32 + quad * 8];
#pragma unroll
      for (int ni = 0; ni < 4; ++ni)
        bf[ni] = *(const s16x8*)&Bs[(wn * 64 + ni * 16 + lane16) * 64 +
                                    kk * 32 + quad * 8];
#pragma unroll
      for (int mi = 0; mi < 4; ++mi)
#pragma unroll
        for (int ni = 0; ni < 4; ++ni)
          acc[mi][ni] = __builtin_amdgcn_mfma_f32_16x16x32_bf16(
              af[mi], bf[ni], acc[mi][ni], 0, 0, 0);
    }
  }

#pragma unroll
  for (int ni = 0; ni < 4; ++ni) {
    const int n = nb0 + wn * 64 + ni * 16 + lane16;
    const float bvx = (omode == 3 && n >= 512) ? bias2[n - 512] : bias[n];
#pragma unroll
    for (int mi = 0; mi < 4; ++mi) {
      const int m0 = mb0 + wm * 64 + mi * 16 + quad * 4;
#pragma unroll
      for (int r = 0; r < 4; ++r) {
        const int m = m0 + r;
        const float v = acc[mi][ni][r] + bvx;
        if (omode == 0) {
          ((short*)C)[(size_t)m * N + n] = f2bf(v);
        } else if (omode == 1) {
          ((float*)C)[(size_t)m * N + n] = v;
        } else {
          if (n < 512) ((short*)C)[(size_t)m * 512 + n] = f2bf(v);
          else         ((short*)C2)[(size_t)m * 512 + (n - 512)] = f2bf(v);
        }
      }
    }
  }
}

// ---------------------------------------------------------------------------
// GEMM (big): 256x256 tile, BK=64, 512 threads = 8 waves (2M x 4N), 8-phase
// schedule (T2+T3+T4+T5). vmcnt(10) ledger audited (r5): each even-phase wait
// retires exactly the half-tiles read two phases later. XCD remap for 8x32.
// omode: 0 = bf16 C; 1 = fp32 C.
// ---------------------------------------------------------------------------
__global__ __launch_bounds__(512, 2) void gemm256_bt(
    const short* __restrict__ A, const short* __restrict__ W,
    const float* __restrict__ bias, void* __restrict__ C,
    int M, int N, int K, int omode)
{
  __shared__ __align__(16) short Asm[2 * 16384];   // [buf][kk][row][32]
  __shared__ __align__(16) short Bsm[2 * 16384];

  const int t = threadIdx.x;
  const int l = t & 63;
  const int w = t >> 6;                // 0..7
  const int lane16 = l & 15;
  const int quad = l >> 4;
  const int wm = w >> 2;               // 0..1
  const int wn = w & 3;                // 0..3

  int bx = blockIdx.x, by = blockIdx.y;
  if (gridDim.x == 8 && gridDim.y == 32) {
    const int bid = blockIdx.y * 8 + blockIdx.x;   // 0..255, x fastest
    const int xcd = bid & 7, idx = bid >> 3;       // idx 0..31
    const int xc = xcd & 3, yc = xcd >> 2;         // 4 x-chunks x 2 y-chunks
    bx = xc * 2 + (idx & 1);                       // 0..7
    by = yc * 16 + (idx >> 1);                     // 0..31
  }
  const int mb0 = by * 256;
  const int nb0 = bx * 256;

  const f32x4 zero = {0.f, 0.f, 0.f, 0.f};
  f32x4 acc[8][4];
#pragma unroll
  for (int i = 0; i < 8; ++i)
#pragma unroll
    for (int j = 0; j < 4; ++j) acc[i][j] = zero;

  const int srow = t >> 2;                       // 0..127
  const int scs = (t & 3) ^ ((t >> 3) & 3);      // pre-swizzled source chunk
  const short* Ag = A + (size_t)(mb0 + srow) * K + scs * 8;
  const short* Wg = W + (size_t)(nb0 + srow) * K + scs * 8;
  const size_t rstep = (size_t)128 * K;

#define STAGE_A(b, kt, kh)                                                    \
  do {                                                                        \
    const size_t ko_ = (size_t)(kt) * 64 + (kh) * 32;                         \
    GLOAD_LDS16(Ag + ko_,         Asm + (b) * 16384 + (kh) * 8192 + t * 8);   \
    GLOAD_LDS16(Ag + ko_ + rstep, Asm + (b) * 16384 + (kh) * 8192 + 4096 + t * 8); \
  } while (0)
#define STAGE_B(b, kt, kh)                                                    \
  do {                                                                        \
    const size_t ko_ = (size_t)(kt) * 64 + (kh) * 32;                         \
    GLOAD_LDS16(Wg + ko_,         Bsm + (b) * 16384 + (kh) * 8192 + t * 8);   \
    GLOAD_LDS16(Wg + ko_ + rstep, Bsm + (b) * 16384 + (kh) * 8192 + 4096 + t * 8); \
  } while (0)

  s16x8 bfr[4];

#define DO_PHASE(BUF, KK, MG, READB, STAGE_STMT, DO_VM)                       \
  {                                                                           \
    const short* Abase = Asm + (BUF) * 16384 + (KK) * 8192;                   \
    const short* Bbase = Bsm + (BUF) * 16384 + (KK) * 8192;                   \
    if (READB) {                                                              \
      _Pragma("unroll")                                                       \
      for (int ni = 0; ni < 4; ++ni) {                                        \
        const int nr = wn * 64 + ni * 16 + lane16;                            \
        bfr[ni] = *(const s16x8*)(Bbase + nr * 32 +                           \
                                  ((quad ^ ((nr >> 1) & 3)) << 3));           \
      }                                                                       \
    }                                                                         \
    s16x8 afr[4];                                                             \
    _Pragma("unroll")                                                         \
    for (int mi2 = 0; mi2 < 4; ++mi2) {                                       \
      const int mr = wm * 128 + (MG) * 64 + mi2 * 16 + lane16;                \
      afr[mi2] = *(const s16x8*)(Abase + mr * 32 +                            \
                                 ((quad ^ ((mr >> 1) & 3)) << 3));            \
    }                                                                         \
    STAGE_STMT;                                                               \
    __builtin_amdgcn_s_barrier();                                             \
    asm volatile("s_waitcnt lgkmcnt(0)" ::: "memory");                        \
    __builtin_amdgcn_sched_barrier(0);                                        \
    __builtin_amdgcn_s_setprio(1);                                            \
    _Pragma("unroll")                                                         \
    for (int mi2 = 0; mi2 < 4; ++mi2)                                         \
      _Pragma("unroll")                                                       \
      for (int ni = 0; ni < 4; ++ni)                                          \
        acc[(MG) * 4 + mi2][ni] = __builtin_amdgcn_mfma_f32_16x16x32_bf16(    \
            afr[mi2], bfr[ni], acc[(MG) * 4 + mi2][ni], 0, 0, 0);             \
    __builtin_amdgcn_s_setprio(0);                                            \
    if (DO_VM) {                                                              \
      asm volatile("s_waitcnt vmcnt(10)" ::: "memory");                       \
      __builtin_amdgcn_sched_barrier(0);                                      \
    }                                                                         \
    __builtin_amdgcn_s_barrier();                                             \
  }

  const int NT = K >> 6;               // K-tiles (even; >= 2)

  STAGE_B(0, 0, 0); STAGE_A(0, 0, 0); STAGE_B(0, 0, 1); STAGE_A(0, 0, 1);
  STAGE_B(1, 1, 0); STAGE_A(1, 1, 0); STAGE_B(1, 1, 1);
  asm volatile("s_waitcnt vmcnt(10)" ::: "memory");
  __builtin_amdgcn_sched_barrier(0);
  __builtin_amdgcn_s_barrier();

  for (int i2 = 0; i2 < NT; i2 += 2) {
    const int tp1 = (i2 + 1 < NT) ? i2 + 1 : NT - 1;
    const int tp2 = (i2 + 2 < NT) ? i2 + 2 : NT - 1;
    const int tp3 = (i2 + 3 < NT) ? i2 + 3 : NT - 1;
    DO_PHASE(0, 0, 0, true,  STAGE_A(1, tp1, 1), false)   // P1
    DO_PHASE(0, 0, 1, false, STAGE_B(0, tp2, 0), true)    // P2
    DO_PHASE(0, 1, 0, true,  STAGE_A(0, tp2, 0), false)   // P3
    DO_PHASE(0, 1, 1, false, STAGE_B(0, tp2, 1), true)    // P4
    DO_PHASE(1, 0, 0, true,  STAGE_A(0, tp2, 1), false)   // P5
    DO_PHASE(1, 0, 1, false, STAGE_B(1, tp3, 0), true)    // P6
    DO_PHASE(1, 1, 0, true,  STAGE_A(1, tp3, 0), false)   // P7
    DO_PHASE(1, 1, 1, false, STAGE_B(1, tp3, 1), true)    // P8
  }

#pragma unroll
  for (int ni = 0; ni < 4; ++ni) {
    const int n = nb0 + wn * 64 + ni * 16 + lane16;
    const float bv = bias[n];
#pragma unroll
    for (int mi = 0; mi < 8; ++mi) {
      const int m0 = mb0 + wm * 128 + mi * 16 + quad * 4;
#pragma unroll
      for (int r = 0; r < 4; ++r) {
        const float v = acc[mi][ni][r] + bv;
        if (omode == 0) ((short*)C)[(size_t)(m0 + r) * N + n] = f2bf(v);
        else            ((float*)C)[(size_t)(m0 + r) * N + n] = v;
      }
    }
  }
#undef DO_PHASE
#undef STAGE_A
#undef STAGE_B
}

// ---------------------------------------------------------------------------
// RoPE cos/sin table: tab[pos*64 + d] = {cos, sin}(pos * invfreq(d)).
// ---------------------------------------------------------------------------
__global__ __launch_bounds__(256) void rope_tab_kernel(float2* __restrict__ tab)
{
  const int i = blockIdx.x * 256 + threadIdx.x;    // 131072
  const int pos = i >> 6, d = i & 63;
  const float fr = (float)pos * exp2f((float)d * -0.20762050593048584f);
  float sn, cs;
  sincosf(fr, &sn, &cs);
  tab[i] = make_float2(cs, sn);
}

// ---------------------------------------------------------------------------
// RoPE in place on bf16 buf[row][head*128 + d], pairs (d, d+64), pos = row%2048.
// (Now used only for K; Q-rope is fused into attn.)
// ---------------------------------------------------------------------------
__global__ __launch_bounds__(256) void rope_kernel(short* __restrict__ buf,
                                                   int lognh,
                                                   const float2* __restrict__ tab)
{
  const int idx = blockIdx.x * 256 + threadIdx.x;
  const int d = idx & 63;
  const int rest = idx >> 6;            // row*nh + h
  const int row = rest >> lognh;
  const int pos = row & 2047;
  const float2 cssn = tab[(pos << 6) | d];
  const float cs = cssn.x, sn = cssn.y;
  const size_t base = (size_t)rest * 128 + d;
  const float lo = bf2f(buf[base]);
  const float hi = bf2f(buf[base + 64]);
  buf[base]      = f2bf(lo * cs - hi * sn);
  buf[base + 64] = f2bf(hi * cs + lo * sn);
}

// ---------------------------------------------------------------------------
// Transpose V: in[m=b*2048+s][n(512)] -> out[(b*512+n)*2048 + s]. 64x64 LDS
// tiles, coalesced 16B on both sides. grid (128, 8), 256 threads.
// ---------------------------------------------------------------------------
__global__ __launch_bounds__(256) void trans_kernel(const short* __restrict__ in,
                                                    short* __restrict__ out)
{
  __shared__ short T[64 * 72];
  const int t = threadIdx.x;
  const int ms = blockIdx.x * 64;   // global m (= b*2048 + s) tile base
  const int ns = blockIdx.y * 64;   // n tile base
  const int b = ms >> 11;
  const int sl = ms & 2047;
  const int r = t >> 3, sg = t & 7;
#pragma unroll
  for (int j = 0; j < 2; ++j) {
    const uint4 v = *(const uint4*)(in + (size_t)(ms + r + 32 * j) * 512 + ns + sg * 8);
    *(uint4*)&T[(r + 32 * j) * 72 + sg * 8] = v;
  }
  __syncthreads();
#pragma unroll
  for (int j = 0; j < 2; ++j) {
    const int nr = r + 32 * j;
    s16x8 v;
#pragma unroll
    for (int i = 0; i < 8; ++i) v[i] = T[(sg * 8 + i) * 72 + nr];
    *(s16x8*)(out + ((size_t)(b * 512 + ns + nr)) * 2048 + sl + sg * 8) = v;
  }
}

// ---------------------------------------------------------------------------
// Flash attention, causal, GQA. r6: DOUBLE-BUFFERED K/V (one barrier per
// tile; buf c^1's last readers passed the barrier at iter-1, so ds_writes to
// c^1 during iter are race-free) + FUSED Q-RoPE (pairs (d,d+64) live in the
// same lane's qf[kk], qf[kk+2] -> in-register rotation via tab; Q is read
// exactly once in attn, so rope cost is amortized over the whole strip).
// XCD remap: each XCD owns two whole (b,kv) groups. In-place og==qg safe.
// ---------------------------------------------------------------------------
__global__ __launch_bounds__(512, 4) void attn_kernel(
    const short* __restrict__ qg, const short* __restrict__ kg,
    const short* __restrict__ vtg, short* __restrict__ og,
    const float2* __restrict__ tab)
{
  __shared__ __align__(16) short Ksm[2 * 64 * 128];   // [buf][key][d], swizzled
  __shared__ __align__(16) short Vsm[2 * 128 * 64];   // [buf][d][key], swizzled
  __shared__ __align__(16) short Psm[128 * 64];       // [q][key], wave-private rows

  const int t = threadIdx.x;
  const int l = t & 63;
  const int w = t >> 6;
  const int lane16 = l & 15;
  const int quad = l >> 4;

  // XCD remap: lid 0..511; group g = (b,kv) 0..15; two groups per XCD.
  const int lid = blockIdx.x + 8 * (blockIdx.y + 16 * blockIdx.z);
  const int xcd = lid & 7, idx = lid >> 3;        // idx 0..63
  const int g = xcd * 2 + (idx >> 5);             // 0..15
  const int wv_ = idx & 31;
  const int b = g >> 2, kv = g & 3;
  const int h = kv * 4 + (wv_ >> 3);
  const int jb = wv_ & 7;

  const int krow = t >> 4, kseg = t & 15;
  const int vrow = t >> 3, vseg = t & 7;
  const int kswz = (kseg ^ (krow & 7)) * 8;
  const int vswz = (vseg ^ (vrow & 7)) * 8;

  const short* kbaseptr = kg + ((size_t)(b * 2048)) * 512 + kv * 128;
  const short* vbaseptr = vtg + ((size_t)(b * 512 + kv * 128)) * 2048;

  const float SC = 0.08838834764831845f * 1.4426950408889634f; // rsqrt(128)*log2e
  const f32x4 zero = {0.f, 0.f, 0.f, 0.f};
  const int swz = (lane16 & 7) << 3;

  uint4 kr0, kr1, vr0, vr1;
#define LOADT(KB)                                                             \
  do {                                                                        \
    kr0 = *(const uint4*)(kbaseptr + (size_t)((KB) + krow) * 512 + kseg * 8); \
    kr1 = *(const uint4*)(kbaseptr + (size_t)((KB) + 32 + krow) * 512 + kseg * 8); \
    vr0 = *(const uint4*)(vbaseptr + (size_t)(vrow) * 2048 + (KB) + vseg * 8);     \
    vr1 = *(const uint4*)(vbaseptr + (size_t)(64 + vrow) * 2048 + (KB) + vseg * 8);\
  } while (0)
#define WRITET(c)                                                             \
  do {                                                                        \
    *(uint4*)&Ksm[(c) * 8192 + krow * 128 + kswz] = kr0;                      \
    *(uint4*)&Ksm[(c) * 8192 + (32 + krow) * 128 + kswz] = kr1;               \
    *(uint4*)&Vsm[(c) * 8192 + vrow * 64 + vswz] = vr0;                       \
    *(uint4*)&Vsm[(c) * 8192 + (64 + vrow) * 64 + vswz] = vr1;                \
  } while (0)

  for (int sp2 = 0; sp2 < 2; ++sp2) {
    const int jj = sp2 ? (15 - jb) : jb;
    const int qb0 = jj * 128;
    const int qw0 = qb0 + w * 16;
    const int qmaxw = qw0 + 15;
    const int ntl = 2 * jj + 2;

    // Q fragments with FUSED RoPE: d = kk*32 + quad*8 + j; pair (d, d+64) is
    // (qf[kk], qf[kk+2]) same lane. pos = qw0+lane16 (row mod 2048).
    s16x8 qf[4];
    {
      const short* qrow =
          qg + ((size_t)(b * 2048 + qw0 + lane16)) * 2048 + h * 128 + quad * 8;
      s16x8 qr[4];
#pragma unroll
      for (int kk = 0; kk < 4; ++kk) qr[kk] = *(const s16x8*)(qrow + kk * 32);
      const float2* tb = tab + (((size_t)(qw0 + lane16)) << 6) + quad * 8;
#pragma unroll
      for (int kk = 0; kk < 2; ++kk) {
        float lo[8], hi[8];
#pragma unroll
        for (int j = 0; j < 8; ++j) {
          const float2 cs2 = tb[kk * 32 + j];
          const float l0 = bf2f(qr[kk][j]);
          const float h0 = bf2f(qr[kk + 2][j]);
          lo[j] = l0 * cs2.x - h0 * cs2.y;
          hi[j] = h0 * cs2.x + l0 * cs2.y;
        }
        union { unsigned int u[4]; s16x8 v; } plo, phi;
#pragma unroll
        for (int j = 0; j < 4; ++j) {
          asm("v_cvt_pk_bf16_f32 %0, %1, %2"
              : "=v"(plo.u[j]) : "v"(lo[2 * j]), "v"(lo[2 * j + 1]));
          asm("v_cvt_pk_bf16_f32 %0, %1, %2"
              : "=v"(phi.u[j]) : "v"(hi[2 * j]), "v"(hi[2 * j + 1]));
        }
        qf[kk] = plo.v;
        qf[kk + 2] = phi.v;
      }
    }

    f32x4 o[8];
#pragma unroll
    for (int i = 0; i < 8; ++i) o[i] = zero;
    float m_i = NEGH, l_i = 0.f;

    // prologue: stage tile 0 into buf 0
    LOADT(0);
    WRITET(0);
    __syncthreads();
    int cur = 0;

    for (int tl = 0; tl < ntl; ++tl) {
      const int kbase = tl * 64;
      if (tl + 1 < ntl) LOADT((tl + 1) * 64);   // issue; flies under compute

      if (kbase <= qmaxw) {
        const short* Kb = Ksm + cur * 8192;
        const short* Vb = Vsm + cur * 8192;
        f32x4 st[4];
#pragma unroll
        for (int mt = 0; mt < 4; ++mt) st[mt] = zero;
        __builtin_amdgcn_s_setprio(1);
#pragma unroll
        for (int mt = 0; mt < 4; ++mt) {
          const int rb = (mt * 16 + lane16) * 128;
#pragma unroll
          for (int kk = 0; kk < 4; ++kk) {
            const s16x8 a = *(const s16x8*)&Kb[rb + ((kk * 32 + quad * 8) ^ swz)];
            st[mt] = __builtin_amdgcn_mfma_f32_16x16x32_bf16(a, qf[kk], st[mt], 0, 0, 0);
          }
        }
        __builtin_amdgcn_s_setprio(0);

        // ---- softmax on raw st (SC folded into exp2 args) ----
        const bool maskt = (kbase + 63 > qw0);
        const int qabs = qw0 + lane16;
        float tl_ = NEGH;
        if (maskt) {
#pragma unroll
          for (int mt = 0; mt < 4; ++mt)
#pragma unroll
            for (int r = 0; r < 4; ++r) {
              float xx = st[mt][r];
              if ((kbase + mt * 16 + quad * 4 + r) > qabs) xx = NEGH;
              st[mt][r] = xx;
              tl_ = fmaxf(tl_, xx);
            }
        } else {
#pragma unroll
          for (int mt = 0; mt < 4; ++mt)
#pragma unroll
            for (int r = 0; r < 4; ++r) tl_ = fmaxf(tl_, st[mt][r]);
        }
        tl_ = fmaxf(tl_, __shfl_xor(tl_, 16));
        tl_ = fmaxf(tl_, __shfl_xor(tl_, 32));
        const float mnew = fmaxf(m_i, tl_);
        // exact skip: if no lane's tile-max exceeds the running max, alpha==1
        if (!__all(tl_ <= m_i)) {
          const float alpha = exp2f((m_i - mnew) * SC);
          l_i *= alpha;
#pragma unroll
          for (int r = 0; r < 4; ++r) {
            const float ar = __shfl(alpha, quad * 4 + r);
#pragma unroll
            for (int ntd = 0; ntd < 8; ++ntd) o[ntd][r] *= ar;
          }
        }
        m_i = mnew;
        const float mS = mnew * SC;
        float rs = 0.f;
#pragma unroll
        for (int mt = 0; mt < 4; ++mt) {
          const float p0 = exp2f(fmaf(st[mt][0], SC, -mS));
          const float p1 = exp2f(fmaf(st[mt][1], SC, -mS));
          const float p2 = exp2f(fmaf(st[mt][2], SC, -mS));
          const float p3 = exp2f(fmaf(st[mt][3], SC, -mS));
          rs += (p0 + p1) + (p2 + p3);
          uint2 pk2;
          asm("v_cvt_pk_bf16_f32 %0, %1, %2" : "=v"(pk2.x) : "v"(p0), "v"(p1));
          asm("v_cvt_pk_bf16_f32 %0, %1, %2" : "=v"(pk2.y) : "v"(p2), "v"(p3));
          *(uint2*)&Psm[(w * 16 + lane16) * 64 + ((mt * 16 + quad * 4) ^ swz)] = pk2;
        }
        rs += __shfl_xor(rs, 16);
        rs += __shfl_xor(rs, 32);
        l_i += rs;

        // PV: O[q][d] += P[q][key] * Vt[d][key]
        const int prb = (w * 16 + lane16) * 64;
        __builtin_amdgcn_s_setprio(1);
#pragma unroll
        for (int kk = 0; kk < 2; ++kk) {
          const s16x8 pf = *(const s16x8*)&Psm[prb + ((kk * 32 + quad * 8) ^ swz)];
#pragma unroll
          for (int ntd = 0; ntd < 8; ++ntd) {
            const s16x8 vf =
                *(const s16x8*)&Vb[(ntd * 16 + lane16) * 64 + ((kk * 32 + quad * 8) ^ swz)];
            o[ntd] = __builtin_amdgcn_mfma_f32_16x16x32_bf16(pf, vf, o[ntd], 0, 0, 0);
          }
        }
        __builtin_amdgcn_s_setprio(0);
      }

      if (tl + 1 < ntl) WRITET(cur ^ 1);   // waits vmcnt internally; buf c^1's
      __syncthreads();                     // last readers passed prev barrier
      cur ^= 1;
    }

    // normalize and store: O row q = quad*4+r, col d = ntd*16+lane16
#pragma unroll
    for (int r = 0; r < 4; ++r) {
      const float lr = __shfl(l_i, quad * 4 + r);
      const float inv = 1.f / lr;
      const size_t base =
          ((size_t)(b * 2048 + qw0 + quad * 4 + r)) * 2048 + h * 128 + lane16;
#pragma unroll
      for (int ntd = 0; ntd < 8; ++ntd) og[base + ntd * 16] = f2bf(o[ntd][r] * inv);
    }
  }
#undef LOADT
#undef WRITET
}

// ---------------------------------------------------------------------------
extern "C" void kernel_launch(void* const* d_in, const int* in_sizes, int n_in,
                              void* d_out, int out_size, void* d_ws,
                              size_t ws_size, hipStream_t stream)
{
  const float* x  = (const float*)d_in[0];
  const float* wq = (const float*)d_in[1];
  const float* bq = (const float*)d_in[2];
  const float* wk = (const float*)d_in[3];
  const float* bk = (const float*)d_in[4];
  const float* wv = (const float*)d_in[5];
  const float* bv = (const float*)d_in[6];
  const float* wo = (const float*)d_in[7];
  const float* bo = (const float*)d_in[8];
  float* out = (float*)d_out;

  // ws layout (77 MiB used; ws_size >= 80 MiB):
  //   xb  @0      32 MiB  [8192][2048] bf16; dead after KV-proj -> wob reuses @0
  //   wqb @32MiB   8 MiB; wkb @40MiB 2 MiB; wvb @42MiB 2 MiB (wkb||wvb = [1024][2048])
  //   qws @44MiB  32 MiB  [8192][2048] bf16; attention output in place
  //   tab @76MiB   1 MiB  float2[2048][64] rope cos/sin
  // d_out doubles as scratch: kws @out+0 8 MiB; vtw @out+8M 8 MiB; vtmp @out+16M 8 MiB
  char* ws = (char*)d_ws;
  short* xb  = (short*)ws;
  short* wqb = (short*)(ws + (32ull << 20));
  short* wkb = (short*)(ws + (40ull << 20));
  short* wvb = (short*)(ws + (42ull << 20));
  short* qws = (short*)(ws + (44ull << 20));
  float2* tab = (float2*)(ws + (76ull << 20));
  short* wob = xb;
  short* kws = (short*)d_out;
  short* vtw = (short*)((char*)d_out + (8ull << 20));
  short* vtmp = (short*)((char*)d_out + (16ull << 20));

  const dim3 blk(256);
  cvt_kernel<<<16384, blk, 0, stream>>>(x,  xb);
  cvt_kernel<<<4096,  blk, 0, stream>>>(wq, wqb);
  cvt_kernel<<<1024,  blk, 0, stream>>>(wk, wkb);
  cvt_kernel<<<1024,  blk, 0, stream>>>(wv, wvb);
  rope_tab_kernel<<<512, blk, 0, stream>>>(tab);
  // projections: Q on 256^2 8-phase; K+V merged (wkb||wvb contiguous), V row-major
  gemm256_bt<<<dim3(8, 32), dim3(512), 0, stream>>>(xb, wqb, bq, qws, 8192, 2048, 2048, 0);
  gemm_bt<<<dim3(8, 64), blk, 0, stream>>>(xb, wkb, bk, bv, kws, vtmp, 8192, 1024, 2048, 3);
  trans_kernel<<<dim3(128, 8), blk, 0, stream>>>(vtmp, vtw);
  rope_kernel<<<8192, blk, 0, stream>>>(kws, 2, tab);   // K only; Q-rope fused in attn
  cvt_kernel<<<4096, blk, 0, stream>>>(wo, wob);
  attn_kernel<<<dim3(8, 16, 4), dim3(512), 0, stream>>>(qws, kws, vtw, qws, tab);
  gemm256_bt<<<dim3(8, 32), dim3(512), 0, stream>>>(qws, wob, bo, out, 8192, 2048, 2048, 1);
}

// Round 7
// 492.778 us; speedup vs baseline: 1.9163x; 1.0246x over previous
//
#include <hip/hip_runtime.h>
#include <stdint.h>
#include <math.h>

typedef __attribute__((ext_vector_type(8))) short s16x8;
typedef __attribute__((ext_vector_type(4))) short s16x4;
typedef __attribute__((ext_vector_type(4))) float f32x4;

#define NEGH (-1.0e30f)

__device__ __forceinline__ short f2bf(float f) {
  union { float f; unsigned int i; } c; c.f = f;
  unsigned int lsb = (c.i >> 16) & 1u;
  c.i += 0x7fffu + lsb;
  return (short)(c.i >> 16);
}
__device__ __forceinline__ float bf2f(short u) {
  union { unsigned int i; float f; } c;
  c.i = ((unsigned int)(unsigned short)u) << 16;
  return c.f;
}

// async global->LDS, 16B per lane. LDS dest must be wave-uniform base + lane*16.
#define GLOAD_LDS16(gp, lp)                                                  \
  __builtin_amdgcn_global_load_lds(                                          \
      (__attribute__((address_space(1))) void*)(void*)(gp),                  \
      (__attribute__((address_space(3))) void*)(lp), 16, 0, 0)

// ---------------------------------------------------------------------------
// fp32 -> bf16 conversion, 4 elements/thread. n must be divisible by 1024.
// ---------------------------------------------------------------------------
__global__ __launch_bounds__(256) void cvt_kernel(const float* __restrict__ in,
                                                  short* __restrict__ out)
{
  const size_t i = ((size_t)blockIdx.x * 256 + threadIdx.x) * 4;
  const float4 v = *(const float4*)(in + i);
  s16x4 o = { f2bf(v.x), f2bf(v.y), f2bf(v.z), f2bf(v.w) };
  *(s16x4*)(out + i) = o;
}

// ---------------------------------------------------------------------------
// Merged weight conversions + rope table (saves 3 launches):
// blocks [0,4096) wq; [4096,5120) wk; [5120,6144) wv; [6144,6656) rope tab.
// ---------------------------------------------------------------------------
__global__ __launch_bounds__(256) void wcvt_kernel(
    const float* __restrict__ wq, const float* __restrict__ wk,
    const float* __restrict__ wv, short* __restrict__ wqb,
    short* __restrict__ wkb, short* __restrict__ wvb,
    float2* __restrict__ tab)
{
  const int bid = blockIdx.x;
  if (bid < 6144) {
    const float* in; short* out; int lb;
    if (bid < 4096)      { in = wq; out = wqb; lb = bid; }
    else if (bid < 5120) { in = wk; out = wkb; lb = bid - 4096; }
    else                 { in = wv; out = wvb; lb = bid - 5120; }
    const size_t i = ((size_t)lb * 256 + threadIdx.x) * 4;
    const float4 v = *(const float4*)(in + i);
    s16x4 o = { f2bf(v.x), f2bf(v.y), f2bf(v.z), f2bf(v.w) };
    *(s16x4*)(out + i) = o;
  } else {
    const int i = (bid - 6144) * 256 + threadIdx.x;   // 131072
    const int d = i & 63;
    const float fr = (float)(i >> 6) * exp2f((float)d * -0.20762050593048584f);
    float sn, cs;
    sincosf(fr, &sn, &cs);
    tab[i] = make_float2(cs, sn);
  }
}

// ---------------------------------------------------------------------------
// GEMM (small-N): C[M,N] = A[M,K] * W[N,K]^T + bias[N]. 128x128 tile, BK=64,
// 256 threads. omode: 0 = bf16 C row-major; 1 = fp32 C row-major;
// 3 = split KV: n<512 -> bf16 C[m*512+n] (bias), n>=512 -> bf16 C2[m*512+n-512]
//     (bias2). XCD remap for grid 8x64 (KV call).
// ---------------------------------------------------------------------------
__global__ __launch_bounds__(256) void gemm_bt(
    const short* __restrict__ A, const short* __restrict__ W,
    const float* __restrict__ bias, const float* __restrict__ bias2,
    void* __restrict__ C, void* __restrict__ C2,
    int M, int N, int K, int omode)
{
  __shared__ __align__(16) short As[128 * 64];
  __shared__ __align__(16) short Bs[128 * 64];

  const int t = threadIdx.x;
  const int l = t & 63;
  const int w = t >> 6;
  const int lane16 = l & 15;
  const int quad = l >> 4;
  const int wm = w >> 1, wn = w & 1;

  int bx = blockIdx.x, by = blockIdx.y;
  if (gridDim.x == 8 && gridDim.y == 64) {       // KV call: XCD-aware remap
    const int lid = blockIdx.x + 8 * blockIdx.y; // 0..511, x fastest
    const int xcd = lid & 7, idx = lid >> 3;     // idx 0..63
    by = xcd * 8 + (idx >> 3);                   // 0..63
    bx = idx & 7;                                // 0..7
  }
  const int mb0 = by * 128;
  const int nb0 = bx * 128;

  const f32x4 zero = {0.f, 0.f, 0.f, 0.f};
  f32x4 acc[4][4];
#pragma unroll
  for (int i = 0; i < 4; ++i)
#pragma unroll
    for (int j = 0; j < 4; ++j) acc[i][j] = zero;

  const int sr = t >> 3;
  const int sp = t & 7;
  const short* Ag = A + (size_t)(mb0 + sr) * K + sp * 8;
  const short* Wg = W + (size_t)(nb0 + sr) * K + sp * 8;
  short* Al = As + t * 8;
  short* Bl = Bs + t * 8;

  const int nkt = K >> 6;
  for (int kt = 0; kt < nkt; ++kt) {
    __syncthreads();
    const int kof = kt * 64;
#pragma unroll
    for (int it = 0; it < 4; ++it) {
      GLOAD_LDS16(Ag + kof + (size_t)(it * 32) * K, Al + it * 2048);
      GLOAD_LDS16(Wg + kof + (size_t)(it * 32) * K, Bl + it * 2048);
    }
    __syncthreads();
#pragma unroll
    for (int kk = 0; kk < 2; ++kk) {
      s16x8 af[4], bf[4];
#pragma unroll
      for (int mi = 0; mi < 4; ++mi)
        af[mi] = *(const s16x8*)&As[(wm * 64 + mi * 16 + lane16) * 64 +
                                    kk * 32 + quad * 8];
#pragma unroll
      for (int ni = 0; ni < 4; ++ni)
        bf[ni] = *(const s16x8*)&Bs[(wn * 64 + ni * 16 + lane16) * 64 +
                                    kk * 32 + quad * 8];
#pragma unroll
      for (int mi = 0; mi < 4; ++mi)
#pragma unroll
        for (int ni = 0; ni < 4; ++ni)
          acc[mi][ni] = __builtin_amdgcn_mfma_f32_16x16x32_bf16(
              af[mi], bf[ni], acc[mi][ni], 0, 0, 0);
    }
  }

#pragma unroll
  for (int ni = 0; ni < 4; ++ni) {
    const int n = nb0 + wn * 64 + ni * 16 + lane16;
    const float bvx = (omode == 3 && n >= 512) ? bias2[n - 512] : bias[n];
#pragma unroll
    for (int mi = 0; mi < 4; ++mi) {
      const int m0 = mb0 + wm * 64 + mi * 16 + quad * 4;
#pragma unroll
      for (int r = 0; r < 4; ++r) {
        const int m = m0 + r;
        const float v = acc[mi][ni][r] + bvx;
        if (omode == 0) {
          ((short*)C)[(size_t)m * N + n] = f2bf(v);
        } else if (omode == 1) {
          ((float*)C)[(size_t)m * N + n] = v;
        } else {
          if (n < 512) ((short*)C)[(size_t)m * 512 + n] = f2bf(v);
          else         ((short*)C2)[(size_t)m * 512 + (n - 512)] = f2bf(v);
        }
      }
    }
  }
}

// ---------------------------------------------------------------------------
// GEMM (big): 256x256 tile, BK=64, 512 threads = 8 waves (2M x 4N), 8-phase
// schedule (T2+T3+T4+T5). r7: template-exact counted vmcnt -- waits ONLY at
// P4 and P8, vmcnt(6) (= 2 loads/stage x 3 stages of slack). Ledger: P4 wait
// (22 in flight -> loads 1-16 retired) covers P5-P8 (need <=16); P8 wait (30
// in flight -> 1-24 retired) covers next P1-P4 (need <=24). Staging-vs-read
// races excluded by the phase-end barriers (writer issues after the barrier
// that retires the region's last reader). XCD remap for grid 8x32.
// omode: 0 = bf16 C; 1 = fp32 C.
// ---------------------------------------------------------------------------
__global__ __launch_bounds__(512, 2) void gemm256_bt(
    const short* __restrict__ A, const short* __restrict__ W,
    const float* __restrict__ bias, void* __restrict__ C,
    int M, int N, int K, int omode)
{
  __shared__ __align__(16) short Asm[2 * 16384];   // [buf][kk][row][32]
  __shared__ __align__(16) short Bsm[2 * 16384];

  const int t = threadIdx.x;
  const int l = t & 63;
  const int w = t >> 6;                // 0..7
  const int lane16 = l & 15;
  const int quad = l >> 4;
  const int wm = w >> 2;               // 0..1
  const int wn = w & 3;                // 0..3

  int bx = blockIdx.x, by = blockIdx.y;
  if (gridDim.x == 8 && gridDim.y == 32) {
    const int bid = blockIdx.y * 8 + blockIdx.x;   // 0..255, x fastest
    const int xcd = bid & 7, idx = bid >> 3;       // idx 0..31
    const int xc = xcd & 3, yc = xcd >> 2;         // 4 x-chunks x 2 y-chunks
    bx = xc * 2 + (idx & 1);                       // 0..7
    by = yc * 16 + (idx >> 1);                     // 0..31
  }
  const int mb0 = by * 256;
  const int nb0 = bx * 256;

  const f32x4 zero = {0.f, 0.f, 0.f, 0.f};
  f32x4 acc[8][4];
#pragma unroll
  for (int i = 0; i < 8; ++i)
#pragma unroll
    for (int j = 0; j < 4; ++j) acc[i][j] = zero;

  const int srow = t >> 2;                       // 0..127
  const int scs = (t & 3) ^ ((t >> 3) & 3);      // pre-swizzled source chunk
  const short* Ag = A + (size_t)(mb0 + srow) * K + scs * 8;
  const short* Wg = W + (size_t)(nb0 + srow) * K + scs * 8;
  const size_t rstep = (size_t)128 * K;

#define STAGE_A(b, kt, kh)                                                    \
  do {                                                                        \
    const size_t ko_ = (size_t)(kt) * 64 + (kh) * 32;                         \
    GLOAD_LDS16(Ag + ko_,         Asm + (b) * 16384 + (kh) * 8192 + t * 8);   \
    GLOAD_LDS16(Ag + ko_ + rstep, Asm + (b) * 16384 + (kh) * 8192 + 4096 + t * 8); \
  } while (0)
#define STAGE_B(b, kt, kh)                                                    \
  do {                                                                        \
    const size_t ko_ = (size_t)(kt) * 64 + (kh) * 32;                         \
    GLOAD_LDS16(Wg + ko_,         Bsm + (b) * 16384 + (kh) * 8192 + t * 8);   \
    GLOAD_LDS16(Wg + ko_ + rstep, Bsm + (b) * 16384 + (kh) * 8192 + 4096 + t * 8); \
  } while (0)

#define VMW6                                                                  \
  asm volatile("s_waitcnt vmcnt(6)" ::: "memory");                            \
  __builtin_amdgcn_sched_barrier(0);

  s16x8 bfr[4];

#define DO_PHASE(BUF, KK, MG, READB, STAGE_STMT, VM_STMT)                     \
  {                                                                           \
    const short* Abase = Asm + (BUF) * 16384 + (KK) * 8192;                   \
    const short* Bbase = Bsm + (BUF) * 16384 + (KK) * 8192;                   \
    if (READB) {                                                              \
      _Pragma("unroll")                                                       \
      for (int ni = 0; ni < 4; ++ni) {                                        \
        const int nr = wn * 64 + ni * 16 + lane16;                            \
        bfr[ni] = *(const s16x8*)(Bbase + nr * 32 +                           \
                                  ((quad ^ ((nr >> 1) & 3)) << 3));           \
      }                                                                       \
    }                                                                         \
    s16x8 afr[4];                                                             \
    _Pragma("unroll")                                                         \
    for (int mi2 = 0; mi2 < 4; ++mi2) {                                       \
      const int mr = wm * 128 + (MG) * 64 + mi2 * 16 + lane16;                \
      afr[mi2] = *(const s16x8*)(Abase + mr * 32 +                            \
                                 ((quad ^ ((mr >> 1) & 3)) << 3));            \
    }                                                                         \
    STAGE_STMT;                                                               \
    __builtin_amdgcn_s_barrier();                                             \
    asm volatile("s_waitcnt lgkmcnt(0)" ::: "memory");                        \
    __builtin_amdgcn_sched_barrier(0);                                        \
    __builtin_amdgcn_s_setprio(1);                                            \
    _Pragma("unroll")                                                         \
    for (int mi2 = 0; mi2 < 4; ++mi2)                                         \
      _Pragma("unroll")                                                       \
      for (int ni = 0; ni < 4; ++ni)                                          \
        acc[(MG) * 4 + mi2][ni] = __builtin_amdgcn_mfma_f32_16x16x32_bf16(    \
            afr[mi2], bfr[ni], acc[(MG) * 4 + mi2][ni], 0, 0, 0);             \
    __builtin_amdgcn_s_setprio(0);                                            \
    VM_STMT                                                                   \
    __builtin_amdgcn_s_barrier();                                             \
  }

  const int NT = K >> 6;               // K-tiles (even; >= 2)

  // prologue: 7 stages (14 loads); wait until buf0 (loads 1-8) landed.
  STAGE_B(0, 0, 0); STAGE_A(0, 0, 0); STAGE_B(0, 0, 1); STAGE_A(0, 0, 1);
  STAGE_B(1, 1, 0); STAGE_A(1, 1, 0); STAGE_B(1, 1, 1);
  asm volatile("s_waitcnt vmcnt(6)" ::: "memory");
  __builtin_amdgcn_sched_barrier(0);
  __builtin_amdgcn_s_barrier();

  for (int i2 = 0; i2 < NT; i2 += 2) {
    const int tp1 = (i2 + 1 < NT) ? i2 + 1 : NT - 1;
    const int tp2 = (i2 + 2 < NT) ? i2 + 2 : NT - 1;
    const int tp3 = (i2 + 3 < NT) ? i2 + 3 : NT - 1;
    DO_PHASE(0, 0, 0, true,  STAGE_A(1, tp1, 1), )        // P1
    DO_PHASE(0, 0, 1, false, STAGE_B(0, tp2, 0), )        // P2
    DO_PHASE(0, 1, 0, true,  STAGE_A(0, tp2, 0), )        // P3
    DO_PHASE(0, 1, 1, false, STAGE_B(0, tp2, 1), VMW6)    // P4
    DO_PHASE(1, 0, 0, true,  STAGE_A(0, tp2, 1), )        // P5
    DO_PHASE(1, 0, 1, false, STAGE_B(1, tp3, 0), )        // P6
    DO_PHASE(1, 1, 0, true,  STAGE_A(1, tp3, 0), )        // P7
    DO_PHASE(1, 1, 1, false, STAGE_B(1, tp3, 1), VMW6)    // P8
  }

#pragma unroll
  for (int ni = 0; ni < 4; ++ni) {
    const int n = nb0 + wn * 64 + ni * 16 + lane16;
    const float bv = bias[n];
#pragma unroll
    for (int mi = 0; mi < 8; ++mi) {
      const int m0 = mb0 + wm * 128 + mi * 16 + quad * 4;
#pragma unroll
      for (int r = 0; r < 4; ++r) {
        const float v = acc[mi][ni][r] + bv;
        if (omode == 0) ((short*)C)[(size_t)(m0 + r) * N + n] = f2bf(v);
        else            ((float*)C)[(size_t)(m0 + r) * N + n] = v;
      }
    }
  }
#undef DO_PHASE
#undef STAGE_A
#undef STAGE_B
#undef VMW6
}

// ---------------------------------------------------------------------------
// RoPE in place on bf16 buf[row][head*128 + d], pairs (d, d+64), pos = row%2048.
// (K only; Q-rope is fused into attn.)
// ---------------------------------------------------------------------------
__global__ __launch_bounds__(256) void rope_kernel(short* __restrict__ buf,
                                                   int lognh,
                                                   const float2* __restrict__ tab)
{
  const int idx = blockIdx.x * 256 + threadIdx.x;
  const int d = idx & 63;
  const int rest = idx >> 6;            // row*nh + h
  const int row = rest >> lognh;
  const int pos = row & 2047;
  const float2 cssn = tab[(pos << 6) | d];
  const float cs = cssn.x, sn = cssn.y;
  const size_t base = (size_t)rest * 128 + d;
  const float lo = bf2f(buf[base]);
  const float hi = bf2f(buf[base + 64]);
  buf[base]      = f2bf(lo * cs - hi * sn);
  buf[base + 64] = f2bf(hi * cs + lo * sn);
}

// ---------------------------------------------------------------------------
// Transpose V: in[m=b*2048+s][n(512)] -> out[(b*512+n)*2048 + s]. 64x64 LDS
// tiles, coalesced 16B on both sides. grid (128, 8), 256 threads.
// ---------------------------------------------------------------------------
__global__ __launch_bounds__(256) void trans_kernel(const short* __restrict__ in,
                                                    short* __restrict__ out)
{
  __shared__ short T[64 * 72];
  const int t = threadIdx.x;
  const int ms = blockIdx.x * 64;   // global m (= b*2048 + s) tile base
  const int ns = blockIdx.y * 64;   // n tile base
  const int b = ms >> 11;
  const int sl = ms & 2047;
  const int r = t >> 3, sg = t & 7;
#pragma unroll
  for (int j = 0; j < 2; ++j) {
    const uint4 v = *(const uint4*)(in + (size_t)(ms + r + 32 * j) * 512 + ns + sg * 8);
    *(uint4*)&T[(r + 32 * j) * 72 + sg * 8] = v;
  }
  __syncthreads();
#pragma unroll
  for (int j = 0; j < 2; ++j) {
    const int nr = r + 32 * j;
    s16x8 v;
#pragma unroll
    for (int i = 0; i < 8; ++i) v[i] = T[(sg * 8 + i) * 72 + nr];
    *(s16x8*)(out + ((size_t)(b * 512 + ns + nr)) * 2048 + sl + sg * 8) = v;
  }
}

// ---------------------------------------------------------------------------
// Flash attention, causal, GQA. r6 structure (double-buffered K/V, one
// barrier/tile, fused Q-RoPE, XCD remap). r7: tree-max (4-level instead of a
// 16-deep serial fmax chain) and hoisted staging pointers (increment instead
// of recompute). In-place og==qg safe.
// ---------------------------------------------------------------------------
__global__ __launch_bounds__(512, 4) void attn_kernel(
    const short* __restrict__ qg, const short* __restrict__ kg,
    const short* __restrict__ vtg, short* __restrict__ og,
    const float2* __restrict__ tab)
{
  __shared__ __align__(16) short Ksm[2 * 64 * 128];   // [buf][key][d], swizzled
  __shared__ __align__(16) short Vsm[2 * 128 * 64];   // [buf][d][key], swizzled
  __shared__ __align__(16) short Psm[128 * 64];       // [q][key], wave-private rows

  const int t = threadIdx.x;
  const int l = t & 63;
  const int w = t >> 6;
  const int lane16 = l & 15;
  const int quad = l >> 4;

  // XCD remap: lid 0..511; group g = (b,kv) 0..15; two groups per XCD.
  const int lid = blockIdx.x + 8 * (blockIdx.y + 16 * blockIdx.z);
  const int xcd = lid & 7, idx = lid >> 3;        // idx 0..63
  const int g = xcd * 2 + (idx >> 5);             // 0..15
  const int wv_ = idx & 31;
  const int b = g >> 2, kv = g & 3;
  const int h = kv * 4 + (wv_ >> 3);
  const int jb = wv_ & 7;

  const int krow = t >> 4, kseg = t & 15;
  const int vrow = t >> 3, vseg = t & 7;
  const int kswz = (kseg ^ (krow & 7)) * 8;
  const int vswz = (vseg ^ (vrow & 7)) * 8;

  const short* kbaseptr = kg + ((size_t)(b * 2048)) * 512 + kv * 128;
  const short* vbaseptr = vtg + ((size_t)(b * 512 + kv * 128)) * 2048;

  const float SC = 0.08838834764831845f * 1.4426950408889634f; // rsqrt(128)*log2e
  const f32x4 zero = {0.f, 0.f, 0.f, 0.f};
  const int swz = (lane16 & 7) << 3;

  uint4 kr0, kr1, vr0, vr1;
#define LOADT()                                                               \
  do {                                                                        \
    kr0 = *(const uint4*)kld;                                                 \
    kr1 = *(const uint4*)(kld + 32 * 512);                                    \
    vr0 = *(const uint4*)vld;                                                 \
    vr1 = *(const uint4*)(vld + 64 * 2048);                                   \
    kld += 64 * 512;                                                          \
    vld += 64;                                                                \
  } while (0)
#define WRITET(c)                                                             \
  do {                                                                        \
    *(uint4*)&Ksm[(c) * 8192 + krow * 128 + kswz] = kr0;                      \
    *(uint4*)&Ksm[(c) * 8192 + (32 + krow) * 128 + kswz] = kr1;               \
    *(uint4*)&Vsm[(c) * 8192 + vrow * 64 + vswz] = vr0;                       \
    *(uint4*)&Vsm[(c) * 8192 + (64 + vrow) * 64 + vswz] = vr1;                \
  } while (0)

  for (int sp2 = 0; sp2 < 2; ++sp2) {
    const int jj = sp2 ? (15 - jb) : jb;
    const int qb0 = jj * 128;
    const int qw0 = qb0 + w * 16;
    const int qmaxw = qw0 + 15;
    const int ntl = 2 * jj + 2;

    // staging pointers for this strip (advance per staged tile)
    const short* kld = kbaseptr + (size_t)krow * 512 + kseg * 8;
    const short* vld = vbaseptr + (size_t)vrow * 2048 + vseg * 8;

    // Q fragments with FUSED RoPE: d = kk*32 + quad*8 + j; pair (d, d+64) is
    // (qf[kk], qf[kk+2]) same lane. pos = qw0+lane16.
    s16x8 qf[4];
    {
      const short* qrow =
          qg + ((size_t)(b * 2048 + qw0 + lane16)) * 2048 + h * 128 + quad * 8;
      s16x8 qr[4];
#pragma unroll
      for (int kk = 0; kk < 4; ++kk) qr[kk] = *(const s16x8*)(qrow + kk * 32);
      const float2* tb = tab + (((size_t)(qw0 + lane16)) << 6) + quad * 8;
#pragma unroll
      for (int kk = 0; kk < 2; ++kk) {
        float lo[8], hi[8];
#pragma unroll
        for (int j = 0; j < 8; ++j) {
          const float2 cs2 = tb[kk * 32 + j];
          const float l0 = bf2f(qr[kk][j]);
          const float h0 = bf2f(qr[kk + 2][j]);
          lo[j] = l0 * cs2.x - h0 * cs2.y;
          hi[j] = h0 * cs2.x + l0 * cs2.y;
        }
        union { unsigned int u[4]; s16x8 v; } plo, phi;
#pragma unroll
        for (int j = 0; j < 4; ++j) {
          asm("v_cvt_pk_bf16_f32 %0, %1, %2"
              : "=v"(plo.u[j]) : "v"(lo[2 * j]), "v"(lo[2 * j + 1]));
          asm("v_cvt_pk_bf16_f32 %0, %1, %2"
              : "=v"(phi.u[j]) : "v"(hi[2 * j]), "v"(hi[2 * j + 1]));
        }
        qf[kk] = plo.v;
        qf[kk + 2] = phi.v;
      }
    }

    f32x4 o[8];
#pragma unroll
    for (int i = 0; i < 8; ++i) o[i] = zero;
    float m_i = NEGH, l_i = 0.f;

    // prologue: stage tile 0 into buf 0
    LOADT();
    WRITET(0);
    __syncthreads();
    int cur = 0;

    for (int tl = 0; tl < ntl; ++tl) {
      const int kbase = tl * 64;
      if (tl + 1 < ntl) LOADT();        // issue; flies under compute

      if (kbase <= qmaxw) {
        const short* Kb = Ksm + cur * 8192;
        const short* Vb = Vsm + cur * 8192;
        f32x4 st[4];
#pragma unroll
        for (int mt = 0; mt < 4; ++mt) st[mt] = zero;
        __builtin_amdgcn_s_setprio(1);
#pragma unroll
        for (int mt = 0; mt < 4; ++mt) {
          const int rb = (mt * 16 + lane16) * 128;
#pragma unroll
          for (int kk = 0; kk < 4; ++kk) {
            const s16x8 a = *(const s16x8*)&Kb[rb + ((kk * 32 + quad * 8) ^ swz)];
            st[mt] = __builtin_amdgcn_mfma_f32_16x16x32_bf16(a, qf[kk], st[mt], 0, 0, 0);
          }
        }
        __builtin_amdgcn_s_setprio(0);

        // ---- softmax on raw st (SC folded into exp2 args), tree max ----
        const bool maskt = (kbase + 63 > qw0);
        const int qabs = qw0 + lane16;
        if (maskt) {
#pragma unroll
          for (int mt = 0; mt < 4; ++mt)
#pragma unroll
            for (int r = 0; r < 4; ++r) {
              if ((kbase + mt * 16 + quad * 4 + r) > qabs) st[mt][r] = NEGH;
            }
        }
        float tm[4];
#pragma unroll
        for (int mt = 0; mt < 4; ++mt)
          tm[mt] = fmaxf(fmaxf(st[mt][0], st[mt][1]),
                         fmaxf(st[mt][2], st[mt][3]));
        float tl_ = fmaxf(fmaxf(tm[0], tm[1]), fmaxf(tm[2], tm[3]));
        tl_ = fmaxf(tl_, __shfl_xor(tl_, 16));
        tl_ = fmaxf(tl_, __shfl_xor(tl_, 32));
        const float mnew = fmaxf(m_i, tl_);
        // exact skip: if no lane's tile-max exceeds the running max, alpha==1
        if (!__all(tl_ <= m_i)) {
          const float alpha = exp2f((m_i - mnew) * SC);
          l_i *= alpha;
#pragma unroll
          for (int r = 0; r < 4; ++r) {
            const float ar = __shfl(alpha, quad * 4 + r);
#pragma unroll
            for (int ntd = 0; ntd < 8; ++ntd) o[ntd][r] *= ar;
          }
        }
        m_i = mnew;
        const float mS = mnew * SC;
        float rs = 0.f;
#pragma unroll
        for (int mt = 0; mt < 4; ++mt) {
          const float p0 = exp2f(fmaf(st[mt][0], SC, -mS));
          const float p1 = exp2f(fmaf(st[mt][1], SC, -mS));
          const float p2 = exp2f(fmaf(st[mt][2], SC, -mS));
          const float p3 = exp2f(fmaf(st[mt][3], SC, -mS));
          rs += (p0 + p1) + (p2 + p3);
          uint2 pk2;
          asm("v_cvt_pk_bf16_f32 %0, %1, %2" : "=v"(pk2.x) : "v"(p0), "v"(p1));
          asm("v_cvt_pk_bf16_f32 %0, %1, %2" : "=v"(pk2.y) : "v"(p2), "v"(p3));
          *(uint2*)&Psm[(w * 16 + lane16) * 64 + ((mt * 16 + quad * 4) ^ swz)] = pk2;
        }
        rs += __shfl_xor(rs, 16);
        rs += __shfl_xor(rs, 32);
        l_i += rs;

        // PV: O[q][d] += P[q][key] * Vt[d][key]
        const int prb = (w * 16 + lane16) * 64;
        __builtin_amdgcn_s_setprio(1);
#pragma unroll
        for (int kk = 0; kk < 2; ++kk) {
          const s16x8 pf = *(const s16x8*)&Psm[prb + ((kk * 32 + quad * 8) ^ swz)];
#pragma unroll
          for (int ntd = 0; ntd < 8; ++ntd) {
            const s16x8 vf =
                *(const s16x8*)&Vb[(ntd * 16 + lane16) * 64 + ((kk * 32 + quad * 8) ^ swz)];
            o[ntd] = __builtin_amdgcn_mfma_f32_16x16x32_bf16(pf, vf, o[ntd], 0, 0, 0);
          }
        }
        __builtin_amdgcn_s_setprio(0);
      }

      if (tl + 1 < ntl) WRITET(cur ^ 1);   // waits vmcnt internally; buf c^1's
      __syncthreads();                     // last readers passed prev barrier
      cur ^= 1;
    }

    // normalize and store: O row q = quad*4+r, col d = ntd*16+lane16
#pragma unroll
    for (int r = 0; r < 4; ++r) {
      const float lr = __shfl(l_i, quad * 4 + r);
      const float inv = 1.f / lr;
      const size_t base =
          ((size_t)(b * 2048 + qw0 + quad * 4 + r)) * 2048 + h * 128 + lane16;
#pragma unroll
      for (int ntd = 0; ntd < 8; ++ntd) og[base + ntd * 16] = f2bf(o[ntd][r] * inv);
    }
  }
#undef LOADT
#undef WRITET
}

// ---------------------------------------------------------------------------
extern "C" void kernel_launch(void* const* d_in, const int* in_sizes, int n_in,
                              void* d_out, int out_size, void* d_ws,
                              size_t ws_size, hipStream_t stream)
{
  const float* x  = (const float*)d_in[0];
  const float* wq = (const float*)d_in[1];
  const float* bq = (const float*)d_in[2];
  const float* wk = (const float*)d_in[3];
  const float* bk = (const float*)d_in[4];
  const float* wv = (const float*)d_in[5];
  const float* bv = (const float*)d_in[6];
  const float* wo = (const float*)d_in[7];
  const float* bo = (const float*)d_in[8];
  float* out = (float*)d_out;

  // ws layout (77 MiB used; ws_size >= 80 MiB):
  //   xb  @0      32 MiB  [8192][2048] bf16; dead after KV-proj -> wob reuses @0
  //   wqb @32MiB   8 MiB; wkb @40MiB 2 MiB; wvb @42MiB 2 MiB (wkb||wvb = [1024][2048])
  //   qws @44MiB  32 MiB  [8192][2048] bf16; attention output in place
  //   tab @76MiB   1 MiB  float2[2048][64] rope cos/sin
  // d_out doubles as scratch: kws @out+0 8 MiB; vtw @out+8M 8 MiB; vtmp @out+16M 8 MiB
  char* ws = (char*)d_ws;
  short* xb  = (short*)ws;
  short* wqb = (short*)(ws + (32ull << 20));
  short* wkb = (short*)(ws + (40ull << 20));
  short* wvb = (short*)(ws + (42ull << 20));
  short* qws = (short*)(ws + (44ull << 20));
  float2* tab = (float2*)(ws + (76ull << 20));
  short* wob = xb;
  short* kws = (short*)d_out;
  short* vtw = (short*)((char*)d_out + (8ull << 20));
  short* vtmp = (short*)((char*)d_out + (16ull << 20));

  const dim3 blk(256);
  cvt_kernel<<<16384, blk, 0, stream>>>(x, xb);
  wcvt_kernel<<<6656, blk, 0, stream>>>(wq, wkb == 0 ? 0 : wk, wv, wqb, wkb, wvb, tab);
  // projections: Q on 256^2 8-phase; K+V merged (wkb||wvb contiguous), V row-major
  gemm256_bt<<<dim3(8, 32), dim3(512), 0, stream>>>(xb, wqb, bq, qws, 8192, 2048, 2048, 0);
  gemm_bt<<<dim3(8, 64), blk, 0, stream>>>(xb, wkb, bk, bv, kws, vtmp, 8192, 1024, 2048, 3);
  trans_kernel<<<dim3(128, 8), blk, 0, stream>>>(vtmp, vtw);
  rope_kernel<<<8192, blk, 0, stream>>>(kws, 2, tab);   // K only; Q-rope fused in attn
  cvt_kernel<<<4096, blk, 0, stream>>>(wo, wob);        // after KV-proj (xb dead)
  attn_kernel<<<dim3(8, 16, 4), dim3(512), 0, stream>>>(qws, kws, vtw, qws, tab);
  gemm256_bt<<<dim3(8, 32), dim3(512), 0, stream>>>(qws, wob, bo, out, 8192, 2048, 2048, 1);
}